// Round 15
// baseline (169.349 us; speedup 1.0000x reference)
//
#include <hip/hip_runtime.h>

#define IN_DIM 128
#define HID 64
#define SHIFT 8                 // 256 nodes per bucket
#define BNODES 256
#define NBMAX 1024              // NB=391 @ N=100k
#define CH 4096                 // edges per block (R9: too big = TLP collapse)
#define SRCMASK 0xFFFFF         // src packed in low 20 bits (N <= 1M)
#define LDSCAP 6144             // csr_place LDS edge-staging capacity (48 KB)

// bf16 round-to-nearest-even
__device__ inline unsigned short f2bf(float f) {
  unsigned u = __float_as_uint(f);
  u += 0x7FFF + ((u >> 16) & 1);
  return (unsigned short)(u >> 16);
}
__device__ inline float bf2f_lo(unsigned v) {   // low bf16 of a packed u32
  return __uint_as_float(v << 16);
}
__device__ inline float bf2f_hi(unsigned v) {   // high bf16 of a packed u32
  return __uint_as_float(v & 0xFFFF0000u);
}

// ---------------- Kernel 1: h1 = bf16(x @ W1 + b1)   [N,128]@[128,64] ----------------
// R15: lane = output column j (0..63 = wave width). W1 read as one SCALAR
// dword per lane per k: 256 B/wave coalesced, ZERO redundancy (R13/R14's
// tx/ty layout re-read each W row 16x -> ~800 MB of L1 transactions; duration
// was invariant under 22%->48% occupancy = per-CU L1 throughput bound).
// x staged in LDS as f32 (straight copy, no quantization); inner-loop x reads
// are same-address broadcasts (free). Wave w handles rows 16w..16w+15.
// R7 lesson: do NOT fuse other stages into this kernel (replay divergence).
__global__ __launch_bounds__(256) void gemm1_kernel(
    const float* __restrict__ x, const float* __restrict__ W1,
    const float* __restrict__ b1, unsigned short* __restrict__ h1, int N) {
  __shared__ float Xs[64][IN_DIM + 4];   // 33.8 KB, stride 132 f32 (16B aligned)

  const int rblk = blockIdx.x * 64;
  for (int idx = threadIdx.x; idx < 64 * 32; idx += 256) {
    int row = idx >> 5, c4 = (idx & 31) * 4;
    int gr = rblk + row;
    if (gr > N - 1) gr = N - 1;          // clamp loads; stores guarded below
    *reinterpret_cast<float4*>(&Xs[row][c4]) =
        *reinterpret_cast<const float4*>(x + (long)gr * IN_DIM + c4);
  }
  __syncthreads();

  const int lane  = threadIdx.x & 63;    // output column j
  const int wbase = (threadIdx.x >> 6) * 16;  // this wave's first row

  float acc[16];
#pragma unroll
  for (int r = 0; r < 16; ++r) acc[r] = 0.f;

#pragma unroll 2
  for (int k4 = 0; k4 < IN_DIM / 4; ++k4) {
    float w0 = W1[(long)(k4 * 4 + 0) * HID + lane];
    float w1 = W1[(long)(k4 * 4 + 1) * HID + lane];
    float w2 = W1[(long)(k4 * 4 + 2) * HID + lane];
    float w3 = W1[(long)(k4 * 4 + 3) * HID + lane];
#pragma unroll
    for (int r = 0; r < 16; ++r) {
      float4 xv = *reinterpret_cast<const float4*>(&Xs[wbase + r][k4 * 4]);
      acc[r] += xv.x * w0;
      acc[r] += xv.y * w1;
      acc[r] += xv.z * w2;
      acc[r] += xv.w * w3;
    }
  }

  const float bb = b1[lane];
#pragma unroll
  for (int r = 0; r < 16; ++r) {
    int gr = rblk + wbase + r;
    if (gr < N) h1[(long)gr * HID + lane] = f2bf(acc[r] + bb);
  }
}

// ------------- Bucket partition pass 1: per-block histogram + reservation -------------
__global__ __launch_bounds__(256) void bucket_count_kernel(
    const int* __restrict__ dst, int* __restrict__ bucket_size,
    int* __restrict__ blockRel, int NB, int E) {
  __shared__ int hist[NBMAX];
  for (int i = threadIdx.x; i < NB; i += 256) hist[i] = 0;
  __syncthreads();
  int base = blockIdx.x * CH;
  int end = min(base + CH, E);
  for (int k = base + threadIdx.x; k < end; k += 256)
    atomicAdd(&hist[dst[k] >> SHIFT], 1);
  __syncthreads();
  for (int i = threadIdx.x; i < NB; i += 256) {
    int c = hist[i];
    int r = c ? atomicAdd(&bucket_size[i], c) : 0;
    blockRel[(long)blockIdx.x * NB + i] = r;
  }
}

// ------------- Pass 2: exclusive scan of bucket sizes (single block) -------------
__global__ __launch_bounds__(1024) void bucket_scan_kernel(
    const int* __restrict__ bucket_size, int* __restrict__ bucket_offs, int NB) {
  __shared__ int tmp[1024];
  int tid = threadIdx.x;
  int v = (tid < NB) ? bucket_size[tid] : 0;
  tmp[tid] = v;
  __syncthreads();
  for (int off = 1; off < 1024; off <<= 1) {
    int t = (tid >= off) ? tmp[tid - off] : 0;
    __syncthreads();
    tmp[tid] += t;
    __syncthreads();
  }
  if (tid <= NB) bucket_offs[tid] = tmp[tid] - v;  // exclusive; offs[NB]=E
}

// ------------- Pass 3: place edges into bucket-partitioned array -------------
// Packed entry: x = src | (dst_local << 20), y = weight bits.
__global__ __launch_bounds__(256) void bucket_place_kernel(
    const int* __restrict__ src, const int* __restrict__ dst,
    const float* __restrict__ w, const int* __restrict__ bucket_offs,
    const int* __restrict__ blockRel, int2* __restrict__ bpart, int NB, int E) {
  __shared__ int cur[NBMAX];
  for (int i = threadIdx.x; i < NB; i += 256)
    cur[i] = bucket_offs[i] + blockRel[(long)blockIdx.x * NB + i];
  __syncthreads();
  int base = blockIdx.x * CH;
  int end = min(base + CH, E);
  for (int k = base + threadIdx.x; k < end; k += 256) {
    int d = dst[k];
    int b = d >> SHIFT;
    int pos = atomicAdd(&cur[b], 1);
    bpart[pos] = make_int2((src[k] & SRCMASK) | ((d & (BNODES - 1)) << 20),
                           __float_as_int(w[k]));
  }
}

// ------------- Pass 4: per-bucket CSR finalize (LDS-staged) -------------
__global__ __launch_bounds__(256) void csr_place_kernel(
    const int2* __restrict__ bpart, const int* __restrict__ bucket_offs,
    int2* __restrict__ csr, int* __restrict__ noffs, int N, int NB, int E) {
  __shared__ int cnt[BNODES];
  __shared__ int cur[BNODES];
  __shared__ int wtot[4];
  __shared__ int2 ebuf[LDSCAP];
  const int t = threadIdx.x;
  const int b = blockIdx.x;
  const int beg = bucket_offs[b], end = bucket_offs[b + 1];
  const int len = end - beg;
  const bool useLds = (len <= LDSCAP);

  cnt[t] = 0;
  __syncthreads();

  if (useLds) {
    for (int k = t; k < len; k += 256) {
      int2 e = bpart[beg + k];
      ebuf[k] = e;
      atomicAdd(&cnt[e.x >> 20], 1);
    }
  } else {
    for (int k = beg + t; k < end; k += 256)
      atomicAdd(&cnt[bpart[k].x >> 20], 1);
  }
  __syncthreads();

  // exclusive scan of cnt[0..255]: per-wave shfl scan + wave-total combine
  int v = cnt[t], s = v;
#pragma unroll
  for (int d = 1; d < 64; d <<= 1) {
    int u = __shfl_up(s, d, 64);
    if ((t & 63) >= d) s += u;
  }
  if ((t & 63) == 63) wtot[t >> 6] = s;
  __syncthreads();
  int base = 0;
  const int wv_ = t >> 6;
  if (wv_ > 0) base += wtot[0];
  if (wv_ > 1) base += wtot[1];
  if (wv_ > 2) base += wtot[2];
  const int g = beg + base + s - v;  // global exclusive offset for node t
  cur[t] = g;
  const int node = (b << SHIFT) + t;
  if (node < N) noffs[node] = g;
  if (b == NB - 1 && t == 0) noffs[N] = E;
  __syncthreads();

  if (useLds) {
    for (int k = t; k < len; k += 256) {
      int2 e = ebuf[k];
      int pos = atomicAdd(&cur[e.x >> 20], 1);
      csr[pos] = make_int2(e.x & SRCMASK, e.y);
    }
  } else {
    for (int k = beg + t; k < end; k += 256) {
      int2 e = bpart[k];
      int pos = atomicAdd(&cur[e.x >> 20], 1);
      csr[pos] = make_int2(e.x & SRCMASK, e.y);
    }
  }
}

// ---------------- Fused: h3[n] = relu(sum_e w*h1[src_e]) . W2 + b2 ----------------
// R13 structure: one 64-lane wave per node, eight 8-lane groups; each group
// handles one edge per step with uint4 loads (8 dims / lane) -> 16 edges in
// flight per wave. Butterfly-with-halving combine, relu*W2, 6-shfl reduce.
// Deterministic, accumulation order fixed by (noffs, csr).
__global__ __launch_bounds__(256) void spmm1_fused_kernel(
    const int* __restrict__ noffs, const int2* __restrict__ csr,
    const unsigned short* __restrict__ h1, const float* __restrict__ W2,
    const float* __restrict__ b2, float* __restrict__ h3, int N) {
  int wave = (blockIdx.x * 256 + threadIdx.x) >> 6;
  int lane = threadIdx.x & 63;
  if (wave >= N) return;
  int beg = noffs[wave], end = noffs[wave + 1];
  const int e8 = lane >> 3;        // eighth 0..7 (edge subset)
  const int l8 = lane & 7;         // dim group: dims 8*l8 .. 8*l8+7

  float a0 = 0.f, a1 = 0.f, a2 = 0.f, a3 = 0.f;
  float a4 = 0.f, a5 = 0.f, a6 = 0.f, a7 = 0.f;
  int k = beg + e8;

  int2 eA, eB;
  if (k + 8 < end) { eA = csr[k]; eB = csr[k + 8]; }
  while (k + 8 < end) {
    uint4 vA = *reinterpret_cast<const uint4*>(h1 + (long)eA.x * HID + 8 * l8);
    uint4 vB = *reinterpret_cast<const uint4*>(h1 + (long)eB.x * HID + 8 * l8);
    float wA = __int_as_float(eA.y), wB = __int_as_float(eB.y);
    int kn = k + 16;
    if (kn + 8 < end) { eA = csr[kn]; eB = csr[kn + 8]; }  // prefetch next pair
    a0 += wA * bf2f_lo(vA.x); a1 += wA * bf2f_hi(vA.x);
    a2 += wA * bf2f_lo(vA.y); a3 += wA * bf2f_hi(vA.y);
    a4 += wA * bf2f_lo(vA.z); a5 += wA * bf2f_hi(vA.z);
    a6 += wA * bf2f_lo(vA.w); a7 += wA * bf2f_hi(vA.w);
    a0 += wB * bf2f_lo(vB.x); a1 += wB * bf2f_hi(vB.x);
    a2 += wB * bf2f_lo(vB.y); a3 += wB * bf2f_hi(vB.y);
    a4 += wB * bf2f_lo(vB.z); a5 += wB * bf2f_hi(vB.z);
    a6 += wB * bf2f_lo(vB.w); a7 += wB * bf2f_hi(vB.w);
    k = kn;
  }
  for (; k < end; k += 8) {
    int2 e = csr[k];
    uint4 v = *reinterpret_cast<const uint4*>(h1 + (long)e.x * HID + 8 * l8);
    float w = __int_as_float(e.y);
    a0 += w * bf2f_lo(v.x); a1 += w * bf2f_hi(v.x);
    a2 += w * bf2f_lo(v.y); a3 += w * bf2f_hi(v.y);
    a4 += w * bf2f_lo(v.z); a5 += w * bf2f_hi(v.z);
    a6 += w * bf2f_lo(v.w); a7 += w * bf2f_hi(v.w);
  }

  // Butterfly combine across eighths, halving live accs each round.
  {
    const bool hi = (e8 & 1);
    float s0 = hi ? a0 : a4;  float r0 = __shfl_xor(s0, 8, 64);
    float s1 = hi ? a1 : a5;  float r1 = __shfl_xor(s1, 8, 64);
    float s2 = hi ? a2 : a6;  float r2 = __shfl_xor(s2, 8, 64);
    float s3 = hi ? a3 : a7;  float r3 = __shfl_xor(s3, 8, 64);
    a0 = (hi ? a4 : a0) + r0;
    a1 = (hi ? a5 : a1) + r1;
    a2 = (hi ? a6 : a2) + r2;
    a3 = (hi ? a7 : a3) + r3;
  }
  {
    const bool hi = (e8 >> 1) & 1;
    float s0 = hi ? a0 : a2;  float r0 = __shfl_xor(s0, 16, 64);
    float s1 = hi ? a1 : a3;  float r1 = __shfl_xor(s1, 16, 64);
    a0 = (hi ? a2 : a0) + r0;
    a1 = (hi ? a3 : a1) + r1;
  }
  {
    const bool hi = (e8 >> 2) & 1;
    float s0 = hi ? a0 : a1;  float r0 = __shfl_xor(s0, 32, 64);
    a0 = (hi ? a1 : a0) + r0;
  }
  const int dim = 8 * l8 + 4 * (e8 & 1) + 2 * ((e8 >> 1) & 1) + ((e8 >> 2) & 1);
  float s = fmaxf(a0, 0.f) * W2[dim];
  s += __shfl_xor(s, 1, 64);
  s += __shfl_xor(s, 2, 64);
  s += __shfl_xor(s, 4, 64);
  s += __shfl_xor(s, 8, 64);
  s += __shfl_xor(s, 16, 64);
  s += __shfl_xor(s, 32, 64);
  if (lane == 0) h3[wave] = s + b2[0];
}

// ---------------- Gather spmm2: out[n] = sum_e w*h3[src_e] ----------------
__global__ __launch_bounds__(256) void spmm2_gather_kernel(
    const int* __restrict__ noffs, const int2* __restrict__ csr,
    const float* __restrict__ h3, float* __restrict__ out, int N) {
  int n = blockIdx.x * 256 + threadIdx.x;
  if (n >= N) return;
  int beg = noffs[n], end = noffs[n + 1];
  float acc = 0.f;
  for (int k = beg; k < end; ++k) {
    int2 e = csr[k];
    acc += __int_as_float(e.y) * h3[e.x];
  }
  out[n] = acc;
}

extern "C" void kernel_launch(void* const* d_in, const int* in_sizes, int n_in,
                              void* d_out, int out_size, void* d_ws, size_t ws_size,
                              hipStream_t stream) {
  const float* x    = (const float*)d_in[0];
  const int*   esrc = (const int*)d_in[1];
  const int*   edst = (const int*)d_in[2];
  const float* ew   = (const float*)d_in[3];
  const float* W1   = (const float*)d_in[4];
  const float* b1   = (const float*)d_in[5];
  const float* W2   = (const float*)d_in[6];
  const float* b2   = (const float*)d_in[7];
  float* out = (float*)d_out;

  const int N = in_sizes[0] / IN_DIM;
  const int E = in_sizes[1];
  const int NB = (N + BNODES - 1) >> SHIFT;         // 391 @ N=100k
  const int PBLK = (E + CH - 1) / CH;               // 391 @ E=1.6M

  char* p = (char*)d_ws;
  auto alloc = [&](size_t bytes) {
    char* r = p;
    p += (bytes + 15) & ~(size_t)15;
    return r;
  };
  unsigned short* h1 = (unsigned short*)alloc((size_t)N * HID * sizeof(unsigned short));
  float* h3          = (float*)alloc((size_t)N * sizeof(float));
  int*   bucket_size = (int*)alloc((size_t)NB * sizeof(int));
  int*   bucket_offs = (int*)alloc((size_t)(NB + 1) * sizeof(int));
  int*   noffs       = (int*)alloc((size_t)(N + 1) * sizeof(int));
  int*   blockRel    = (int*)alloc((size_t)PBLK * NB * sizeof(int));
  int2*  bpart       = (int2*)alloc((size_t)E * sizeof(int2));
  int2*  csr         = (int2*)alloc((size_t)E * sizeof(int2));

  hipMemsetAsync(bucket_size, 0, (size_t)NB * sizeof(int), stream);

  gemm1_kernel<<<(N + 63) / 64, 256, 0, stream>>>(x, W1, b1, h1, N);

  bucket_count_kernel<<<PBLK, 256, 0, stream>>>(edst, bucket_size, blockRel, NB, E);
  bucket_scan_kernel<<<1, 1024, 0, stream>>>(bucket_size, bucket_offs, NB);
  bucket_place_kernel<<<PBLK, 256, 0, stream>>>(esrc, edst, ew, bucket_offs,
                                                blockRel, bpart, NB, E);
  csr_place_kernel<<<NB, 256, 0, stream>>>(bpart, bucket_offs, csr, noffs, N, NB, E);

  spmm1_fused_kernel<<<(unsigned)(((long)N * 64 + 255) / 256), 256, 0, stream>>>(
      noffs, csr, h1, W2, b2, h3, N);

  spmm2_gather_kernel<<<(N + 255) / 256, 256, 0, stream>>>(noffs, csr, h3, out, N);
}

// Round 16
// 135.789 us; speedup vs baseline: 1.2472x; 1.2472x over previous
//
#include <hip/hip_runtime.h>

#define IN_DIM 128
#define HID 64
#define SHIFT 8                 // 256 nodes per bucket
#define BNODES 256
#define NBMAX 1024              // NB=391 @ N=100k
#define CH 4096                 // edges per block (R9: too big = TLP collapse)
#define SRCMASK 0xFFFFF         // src packed in low 20 bits (N <= 1M)
#define LDSCAP 6144             // csr_place LDS edge-staging capacity (48 KB)

using bf16x8 = __attribute__((ext_vector_type(8))) short;   // 8 bf16 (4 VGPRs)
using f32x4  = __attribute__((ext_vector_type(4))) float;

// bf16 round-to-nearest-even
__device__ inline unsigned short f2bf(float f) {
  unsigned u = __float_as_uint(f);
  u += 0x7FFF + ((u >> 16) & 1);
  return (unsigned short)(u >> 16);
}
__device__ inline float bf2f_lo(unsigned v) {   // low bf16 of a packed u32
  return __uint_as_float(v << 16);
}
__device__ inline float bf2f_hi(unsigned v) {   // high bf16 of a packed u32
  return __uint_as_float(v & 0xFFFF0000u);
}

// ---------------- Prep: pack W1 into MFMA B-fragment order ----------------
// W1b flat idx = ((jt*4 + kc)*64 + lane)*8 + i  ->  per-lane uint4 coalesced.
// B-frag mapping (canonical CDNA): col = lane&15, k = (lane>>4)*8 + i.
__global__ __launch_bounds__(256) void w1pack_kernel(
    const float* __restrict__ W1, unsigned short* __restrict__ W1b) {
  int idx = blockIdx.x * 256 + threadIdx.x;   // 8192 total
  if (idx >= 4 * 4 * 64 * 8) return;
  int i    = idx & 7;
  int lane = (idx >> 3) & 63;
  int kc   = (idx >> 9) & 3;
  int jt   = idx >> 11;
  int k = kc * 32 + ((lane >> 4) << 3) + i;
  int n = jt * 16 + (lane & 15);
  W1b[idx] = f2bf(W1[k * HID + n]);
}

// ---------------- Kernel 1: h1 = bf16(x @ W1 + b1) via MFMA ----------------
// R16: matrix cores instead of vector FMA (R13-R15 all hit a ~45-69 us
// structural floor on the VALU path). Block = 256 thr = 4 waves; wave w owns
// rows rblk+16w..+15. Per wave: A-frags loaded straight from global x (8
// contiguous f32 -> bf16; each x element read once per block, no LDS, no
// barrier); B-frags from pre-packed W1b (16 KB, L1-resident, uint4/lane).
// 4 col-tiles x 4 K-chunks = 16 mfma_f32_16x16x32_bf16 per wave.
// A: row=lane&15, k=(lane>>4)*8+i.  C/D (m89-verified): col=lane&15,
// row=(lane>>4)*4+reg.
// R7 lesson: do NOT fuse other stages into this kernel (replay divergence).
__global__ __launch_bounds__(256) void gemm1_kernel(
    const float* __restrict__ x, const unsigned short* __restrict__ W1b,
    const float* __restrict__ b1, unsigned short* __restrict__ h1, int N) {
  const int lane = threadIdx.x & 63;
  const int g16  = threadIdx.x >> 6;          // wave id: rows g16*16..+15
  const int rblk = blockIdx.x * 64;
  const int arow = rblk + g16 * 16 + (lane & 15);
  const int kbase = (lane >> 4) * 8;

  long ar = (arow > N - 1) ? (N - 1) : arow;  // clamp loads; stores guarded
  const float* xrow = x + ar * IN_DIM;

  bf16x8 a[4];
#pragma unroll
  for (int kc = 0; kc < 4; ++kc) {
    float4 v0 = *reinterpret_cast<const float4*>(xrow + kc * 32 + kbase);
    float4 v1 = *reinterpret_cast<const float4*>(xrow + kc * 32 + kbase + 4);
    bf16x8 t;
    t[0] = (short)f2bf(v0.x); t[1] = (short)f2bf(v0.y);
    t[2] = (short)f2bf(v0.z); t[3] = (short)f2bf(v0.w);
    t[4] = (short)f2bf(v1.x); t[5] = (short)f2bf(v1.y);
    t[6] = (short)f2bf(v1.z); t[7] = (short)f2bf(v1.w);
    a[kc] = t;
  }

  const uint4* wb = reinterpret_cast<const uint4*>(W1b);
#pragma unroll
  for (int jt = 0; jt < 4; ++jt) {
    f32x4 acc = {0.f, 0.f, 0.f, 0.f};
#pragma unroll
    for (int kc = 0; kc < 4; ++kc) {
      union { uint4 q; bf16x8 v; } bu;
      bu.q = wb[(jt * 4 + kc) * 64 + lane];
      acc = __builtin_amdgcn_mfma_f32_16x16x32_bf16(a[kc], bu.v, acc, 0, 0, 0);
    }
    const int col = jt * 16 + (lane & 15);
    const float bb = b1[col];
#pragma unroll
    for (int r = 0; r < 4; ++r) {
      int row = (lane >> 4) * 4 + r;
      int gr = rblk + g16 * 16 + row;
      if (gr < N) h1[(long)gr * HID + col] = f2bf(acc[r] + bb);
    }
  }
}

// ------------- Bucket partition pass 1: per-block histogram + reservation -------------
__global__ __launch_bounds__(256) void bucket_count_kernel(
    const int* __restrict__ dst, int* __restrict__ bucket_size,
    int* __restrict__ blockRel, int NB, int E) {
  __shared__ int hist[NBMAX];
  for (int i = threadIdx.x; i < NB; i += 256) hist[i] = 0;
  __syncthreads();
  int base = blockIdx.x * CH;
  int end = min(base + CH, E);
  for (int k = base + threadIdx.x; k < end; k += 256)
    atomicAdd(&hist[dst[k] >> SHIFT], 1);
  __syncthreads();
  for (int i = threadIdx.x; i < NB; i += 256) {
    int c = hist[i];
    int r = c ? atomicAdd(&bucket_size[i], c) : 0;
    blockRel[(long)blockIdx.x * NB + i] = r;
  }
}

// ------------- Pass 2: exclusive scan of bucket sizes (single block) -------------
__global__ __launch_bounds__(1024) void bucket_scan_kernel(
    const int* __restrict__ bucket_size, int* __restrict__ bucket_offs, int NB) {
  __shared__ int tmp[1024];
  int tid = threadIdx.x;
  int v = (tid < NB) ? bucket_size[tid] : 0;
  tmp[tid] = v;
  __syncthreads();
  for (int off = 1; off < 1024; off <<= 1) {
    int t = (tid >= off) ? tmp[tid - off] : 0;
    __syncthreads();
    tmp[tid] += t;
    __syncthreads();
  }
  if (tid <= NB) bucket_offs[tid] = tmp[tid] - v;  // exclusive; offs[NB]=E
}

// ------------- Pass 3: place edges into bucket-partitioned array -------------
// Packed entry: x = src | (dst_local << 20), y = weight bits.
__global__ __launch_bounds__(256) void bucket_place_kernel(
    const int* __restrict__ src, const int* __restrict__ dst,
    const float* __restrict__ w, const int* __restrict__ bucket_offs,
    const int* __restrict__ blockRel, int2* __restrict__ bpart, int NB, int E) {
  __shared__ int cur[NBMAX];
  for (int i = threadIdx.x; i < NB; i += 256)
    cur[i] = bucket_offs[i] + blockRel[(long)blockIdx.x * NB + i];
  __syncthreads();
  int base = blockIdx.x * CH;
  int end = min(base + CH, E);
  for (int k = base + threadIdx.x; k < end; k += 256) {
    int d = dst[k];
    int b = d >> SHIFT;
    int pos = atomicAdd(&cur[b], 1);
    bpart[pos] = make_int2((src[k] & SRCMASK) | ((d & (BNODES - 1)) << 20),
                           __float_as_int(w[k]));
  }
}

// ------------- Pass 4: per-bucket CSR finalize (LDS-staged) -------------
__global__ __launch_bounds__(256) void csr_place_kernel(
    const int2* __restrict__ bpart, const int* __restrict__ bucket_offs,
    int2* __restrict__ csr, int* __restrict__ noffs, int N, int NB, int E) {
  __shared__ int cnt[BNODES];
  __shared__ int cur[BNODES];
  __shared__ int wtot[4];
  __shared__ int2 ebuf[LDSCAP];
  const int t = threadIdx.x;
  const int b = blockIdx.x;
  const int beg = bucket_offs[b], end = bucket_offs[b + 1];
  const int len = end - beg;
  const bool useLds = (len <= LDSCAP);

  cnt[t] = 0;
  __syncthreads();

  if (useLds) {
    for (int k = t; k < len; k += 256) {
      int2 e = bpart[beg + k];
      ebuf[k] = e;
      atomicAdd(&cnt[e.x >> 20], 1);
    }
  } else {
    for (int k = beg + t; k < end; k += 256)
      atomicAdd(&cnt[bpart[k].x >> 20], 1);
  }
  __syncthreads();

  // exclusive scan of cnt[0..255]: per-wave shfl scan + wave-total combine
  int v = cnt[t], s = v;
#pragma unroll
  for (int d = 1; d < 64; d <<= 1) {
    int u = __shfl_up(s, d, 64);
    if ((t & 63) >= d) s += u;
  }
  if ((t & 63) == 63) wtot[t >> 6] = s;
  __syncthreads();
  int base = 0;
  const int wv_ = t >> 6;
  if (wv_ > 0) base += wtot[0];
  if (wv_ > 1) base += wtot[1];
  if (wv_ > 2) base += wtot[2];
  const int g = beg + base + s - v;  // global exclusive offset for node t
  cur[t] = g;
  const int node = (b << SHIFT) + t;
  if (node < N) noffs[node] = g;
  if (b == NB - 1 && t == 0) noffs[N] = E;
  __syncthreads();

  if (useLds) {
    for (int k = t; k < len; k += 256) {
      int2 e = ebuf[k];
      int pos = atomicAdd(&cur[e.x >> 20], 1);
      csr[pos] = make_int2(e.x & SRCMASK, e.y);
    }
  } else {
    for (int k = beg + t; k < end; k += 256) {
      int2 e = bpart[k];
      int pos = atomicAdd(&cur[e.x >> 20], 1);
      csr[pos] = make_int2(e.x & SRCMASK, e.y);
    }
  }
}

// ---------------- Fused: h3[n] = relu(sum_e w*h1[src_e]) . W2 + b2 ----------------
// R13 structure: one 64-lane wave per node, eight 8-lane groups; each group
// handles one edge per step with uint4 loads (8 dims / lane) -> 16 edges in
// flight per wave. Butterfly-with-halving combine, relu*W2, 6-shfl reduce.
// Deterministic, accumulation order fixed by (noffs, csr).
__global__ __launch_bounds__(256) void spmm1_fused_kernel(
    const int* __restrict__ noffs, const int2* __restrict__ csr,
    const unsigned short* __restrict__ h1, const float* __restrict__ W2,
    const float* __restrict__ b2, float* __restrict__ h3, int N) {
  int wave = (blockIdx.x * 256 + threadIdx.x) >> 6;
  int lane = threadIdx.x & 63;
  if (wave >= N) return;
  int beg = noffs[wave], end = noffs[wave + 1];
  const int e8 = lane >> 3;        // eighth 0..7 (edge subset)
  const int l8 = lane & 7;         // dim group: dims 8*l8 .. 8*l8+7

  float a0 = 0.f, a1 = 0.f, a2 = 0.f, a3 = 0.f;
  float a4 = 0.f, a5 = 0.f, a6 = 0.f, a7 = 0.f;
  int k = beg + e8;

  int2 eA, eB;
  if (k + 8 < end) { eA = csr[k]; eB = csr[k + 8]; }
  while (k + 8 < end) {
    uint4 vA = *reinterpret_cast<const uint4*>(h1 + (long)eA.x * HID + 8 * l8);
    uint4 vB = *reinterpret_cast<const uint4*>(h1 + (long)eB.x * HID + 8 * l8);
    float wA = __int_as_float(eA.y), wB = __int_as_float(eB.y);
    int kn = k + 16;
    if (kn + 8 < end) { eA = csr[kn]; eB = csr[kn + 8]; }  // prefetch next pair
    a0 += wA * bf2f_lo(vA.x); a1 += wA * bf2f_hi(vA.x);
    a2 += wA * bf2f_lo(vA.y); a3 += wA * bf2f_hi(vA.y);
    a4 += wA * bf2f_lo(vA.z); a5 += wA * bf2f_hi(vA.z);
    a6 += wA * bf2f_lo(vA.w); a7 += wA * bf2f_hi(vA.w);
    a0 += wB * bf2f_lo(vB.x); a1 += wB * bf2f_hi(vB.x);
    a2 += wB * bf2f_lo(vB.y); a3 += wB * bf2f_hi(vB.y);
    a4 += wB * bf2f_lo(vB.z); a5 += wB * bf2f_hi(vB.z);
    a6 += wB * bf2f_lo(vB.w); a7 += wB * bf2f_hi(vB.w);
    k = kn;
  }
  for (; k < end; k += 8) {
    int2 e = csr[k];
    uint4 v = *reinterpret_cast<const uint4*>(h1 + (long)e.x * HID + 8 * l8);
    float w = __int_as_float(e.y);
    a0 += w * bf2f_lo(v.x); a1 += w * bf2f_hi(v.x);
    a2 += w * bf2f_lo(v.y); a3 += w * bf2f_hi(v.y);
    a4 += w * bf2f_lo(v.z); a5 += w * bf2f_hi(v.z);
    a6 += w * bf2f_lo(v.w); a7 += w * bf2f_hi(v.w);
  }

  // Butterfly combine across eighths, halving live accs each round.
  {
    const bool hi = (e8 & 1);
    float s0 = hi ? a0 : a4;  float r0 = __shfl_xor(s0, 8, 64);
    float s1 = hi ? a1 : a5;  float r1 = __shfl_xor(s1, 8, 64);
    float s2 = hi ? a2 : a6;  float r2 = __shfl_xor(s2, 8, 64);
    float s3 = hi ? a3 : a7;  float r3 = __shfl_xor(s3, 8, 64);
    a0 = (hi ? a4 : a0) + r0;
    a1 = (hi ? a5 : a1) + r1;
    a2 = (hi ? a6 : a2) + r2;
    a3 = (hi ? a7 : a3) + r3;
  }
  {
    const bool hi = (e8 >> 1) & 1;
    float s0 = hi ? a0 : a2;  float r0 = __shfl_xor(s0, 16, 64);
    float s1 = hi ? a1 : a3;  float r1 = __shfl_xor(s1, 16, 64);
    a0 = (hi ? a2 : a0) + r0;
    a1 = (hi ? a3 : a1) + r1;
  }
  {
    const bool hi = (e8 >> 2) & 1;
    float s0 = hi ? a0 : a1;  float r0 = __shfl_xor(s0, 32, 64);
    a0 = (hi ? a1 : a0) + r0;
  }
  const int dim = 8 * l8 + 4 * (e8 & 1) + 2 * ((e8 >> 1) & 1) + ((e8 >> 2) & 1);
  float s = fmaxf(a0, 0.f) * W2[dim];
  s += __shfl_xor(s, 1, 64);
  s += __shfl_xor(s, 2, 64);
  s += __shfl_xor(s, 4, 64);
  s += __shfl_xor(s, 8, 64);
  s += __shfl_xor(s, 16, 64);
  s += __shfl_xor(s, 32, 64);
  if (lane == 0) h3[wave] = s + b2[0];
}

// ---------------- Gather spmm2: out[n] = sum_e w*h3[src_e] ----------------
__global__ __launch_bounds__(256) void spmm2_gather_kernel(
    const int* __restrict__ noffs, const int2* __restrict__ csr,
    const float* __restrict__ h3, float* __restrict__ out, int N) {
  int n = blockIdx.x * 256 + threadIdx.x;
  if (n >= N) return;
  int beg = noffs[n], end = noffs[n + 1];
  float acc = 0.f;
  for (int k = beg; k < end; ++k) {
    int2 e = csr[k];
    acc += __int_as_float(e.y) * h3[e.x];
  }
  out[n] = acc;
}

extern "C" void kernel_launch(void* const* d_in, const int* in_sizes, int n_in,
                              void* d_out, int out_size, void* d_ws, size_t ws_size,
                              hipStream_t stream) {
  const float* x    = (const float*)d_in[0];
  const int*   esrc = (const int*)d_in[1];
  const int*   edst = (const int*)d_in[2];
  const float* ew   = (const float*)d_in[3];
  const float* W1   = (const float*)d_in[4];
  const float* b1   = (const float*)d_in[5];
  const float* W2   = (const float*)d_in[6];
  const float* b2   = (const float*)d_in[7];
  float* out = (float*)d_out;

  const int N = in_sizes[0] / IN_DIM;
  const int E = in_sizes[1];
  const int NB = (N + BNODES - 1) >> SHIFT;         // 391 @ N=100k
  const int PBLK = (E + CH - 1) / CH;               // 391 @ E=1.6M

  char* p = (char*)d_ws;
  auto alloc = [&](size_t bytes) {
    char* r = p;
    p += (bytes + 15) & ~(size_t)15;
    return r;
  };
  unsigned short* h1 = (unsigned short*)alloc((size_t)N * HID * sizeof(unsigned short));
  unsigned short* W1b= (unsigned short*)alloc((size_t)8192 * sizeof(unsigned short));
  float* h3          = (float*)alloc((size_t)N * sizeof(float));
  int*   bucket_size = (int*)alloc((size_t)NB * sizeof(int));
  int*   bucket_offs = (int*)alloc((size_t)(NB + 1) * sizeof(int));
  int*   noffs       = (int*)alloc((size_t)(N + 1) * sizeof(int));
  int*   blockRel    = (int*)alloc((size_t)PBLK * NB * sizeof(int));
  int2*  bpart       = (int2*)alloc((size_t)E * sizeof(int2));
  int2*  csr         = (int2*)alloc((size_t)E * sizeof(int2));

  hipMemsetAsync(bucket_size, 0, (size_t)NB * sizeof(int), stream);

  w1pack_kernel<<<32, 256, 0, stream>>>(W1, W1b);
  gemm1_kernel<<<(N + 63) / 64, 256, 0, stream>>>(x, W1b, b1, h1, N);

  bucket_count_kernel<<<PBLK, 256, 0, stream>>>(edst, bucket_size, blockRel, NB, E);
  bucket_scan_kernel<<<1, 1024, 0, stream>>>(bucket_size, bucket_offs, NB);
  bucket_place_kernel<<<PBLK, 256, 0, stream>>>(esrc, edst, ew, bucket_offs,
                                                blockRel, bpart, NB, E);
  csr_place_kernel<<<NB, 256, 0, stream>>>(bpart, bucket_offs, csr, noffs, N, NB, E);

  spmm1_fused_kernel<<<(unsigned)(((long)N * 64 + 255) / 256), 256, 0, stream>>>(
      noffs, csr, h1, W2, b2, h3, N);

  spmm2_gather_kernel<<<(N + 255) / 256, 256, 0, stream>>>(noffs, csr, h3, out, N);
}

// Round 17
// 135.109 us; speedup vs baseline: 1.2534x; 1.0050x over previous
//
#include <hip/hip_runtime.h>

#define IN_DIM 128
#define HID 64
#define SHIFT 8                 // 256 nodes per bucket
#define BNODES 256
#define NBMAX 1024              // NB=391 @ N=100k
#define CH 4096                 // edges per block (R9: too big = TLP collapse)
#define SRCMASK 0xFFFFF         // src packed in low 20 bits (N <= 1M)
#define LDSCAP 6144             // csr_place LDS edge-staging capacity (48 KB)
#define XSTR 130                // Xs row stride in shorts (65 dwords, odd -> <=4-way)

using bf16x8 = __attribute__((ext_vector_type(8))) short;   // 8 bf16 (4 VGPRs)
using f32x4  = __attribute__((ext_vector_type(4))) float;

// bf16 round-to-nearest-even
__device__ inline unsigned short f2bf(float f) {
  unsigned u = __float_as_uint(f);
  u += 0x7FFF + ((u >> 16) & 1);
  return (unsigned short)(u >> 16);
}
__device__ inline float bf2f_lo(unsigned v) {   // low bf16 of a packed u32
  return __uint_as_float(v << 16);
}
__device__ inline float bf2f_hi(unsigned v) {   // high bf16 of a packed u32
  return __uint_as_float(v & 0xFFFF0000u);
}

// ---------------- Prep: pack W1 into MFMA B-fragment order ----------------
// W1b flat idx = ((jt*4 + kc)*64 + lane)*8 + i  ->  per-lane uint4 coalesced.
// B-frag mapping: col = lane&15, k = (lane>>4)*8 + i.
__global__ __launch_bounds__(256) void w1pack_kernel(
    const float* __restrict__ W1, unsigned short* __restrict__ W1b) {
  int idx = blockIdx.x * 256 + threadIdx.x;   // 8192 total
  if (idx >= 4 * 4 * 64 * 8) return;
  int i    = idx & 7;
  int lane = (idx >> 3) & 63;
  int kc   = (idx >> 9) & 3;
  int jt   = idx >> 11;
  int k = kc * 32 + ((lane >> 4) << 3) + i;
  int n = jt * 16 + (lane & 15);
  W1b[idx] = f2bf(W1[k * HID + n]);
}

// ---------------- Kernel 1: h1 = bf16(x @ W1 + b1) via MFMA ----------------
// R17: R16's MFMA structure + COALESCED per-wave LDS staging of x. R16's
// direct A-frag loads had consecutive lanes reading consecutive ROWS (512 B
// stride, 32 B/lane) -> ~50% HBM efficiency, gemm1 ~28 us. Now each wave
// stages its 16 rows coalesced (lanes sweep float4 along a row), converts to
// bf16 in a 4 KB LDS slice, then ds_read_b128 per A-frag. Loads become
// pure-BW (~64 MB total).
// R7 lesson: do NOT fuse other stages into this kernel (replay divergence).
__global__ __launch_bounds__(256) void gemm1_kernel(
    const float* __restrict__ x, const unsigned short* __restrict__ W1b,
    const float* __restrict__ b1, unsigned short* __restrict__ h1, int N) {
  __shared__ unsigned short Xs[4][16][XSTR];   // 16.6 KB
  const int lane = threadIdx.x & 63;
  const int w    = threadIdx.x >> 6;           // wave id: rows 16w..16w+15
  const int rblk = blockIdx.x * 64;

  // ---- coalesced staging: 512 float4 per wave, 8 iters, lane-consecutive c4
  for (int it = 0; it < 8; ++it) {
    int flat = it * 64 + lane;                 // 0..511
    int row  = flat >> 5;                      // 32 float4 per row
    int c4   = (flat & 31) * 4;
    int gr = rblk + w * 16 + row;
    if (gr > N - 1) gr = N - 1;                // clamp loads; stores guarded
    float4 v = *reinterpret_cast<const float4*>(x + (long)gr * IN_DIM + c4);
    ushort4 o;
    o.x = f2bf(v.x); o.y = f2bf(v.y); o.z = f2bf(v.z); o.w = f2bf(v.w);
    *reinterpret_cast<ushort4*>(&Xs[w][row][c4]) = o;
  }
  __syncthreads();

  // ---- A-frags from LDS: lane l row l&15, k-chunk base (l>>4)*8
  bf16x8 a[4];
#pragma unroll
  for (int kc = 0; kc < 4; ++kc) {
    a[kc] = *reinterpret_cast<const bf16x8*>(
        &Xs[w][lane & 15][kc * 32 + ((lane >> 4) << 3)]);
  }

  const uint4* wb = reinterpret_cast<const uint4*>(W1b);
#pragma unroll
  for (int jt = 0; jt < 4; ++jt) {
    f32x4 acc = {0.f, 0.f, 0.f, 0.f};
#pragma unroll
    for (int kc = 0; kc < 4; ++kc) {
      union { uint4 q; bf16x8 v; } bu;
      bu.q = wb[(jt * 4 + kc) * 64 + lane];
      acc = __builtin_amdgcn_mfma_f32_16x16x32_bf16(a[kc], bu.v, acc, 0, 0, 0);
    }
    const int col = jt * 16 + (lane & 15);
    const float bb = b1[col];
#pragma unroll
    for (int r = 0; r < 4; ++r) {
      int row = (lane >> 4) * 4 + r;
      int gr = rblk + w * 16 + row;
      if (gr < N) h1[(long)gr * HID + col] = f2bf(acc[r] + bb);
    }
  }
}

// ------------- Bucket partition pass 1: per-block histogram + reservation -------------
__global__ __launch_bounds__(256) void bucket_count_kernel(
    const int* __restrict__ dst, int* __restrict__ bucket_size,
    int* __restrict__ blockRel, int NB, int E) {
  __shared__ int hist[NBMAX];
  for (int i = threadIdx.x; i < NB; i += 256) hist[i] = 0;
  __syncthreads();
  int base = blockIdx.x * CH;
  int end = min(base + CH, E);
  for (int k = base + threadIdx.x; k < end; k += 256)
    atomicAdd(&hist[dst[k] >> SHIFT], 1);
  __syncthreads();
  for (int i = threadIdx.x; i < NB; i += 256) {
    int c = hist[i];
    int r = c ? atomicAdd(&bucket_size[i], c) : 0;
    blockRel[(long)blockIdx.x * NB + i] = r;
  }
}

// ------------- Pass 2: exclusive scan of bucket sizes (single block) -------------
__global__ __launch_bounds__(1024) void bucket_scan_kernel(
    const int* __restrict__ bucket_size, int* __restrict__ bucket_offs, int NB) {
  __shared__ int tmp[1024];
  int tid = threadIdx.x;
  int v = (tid < NB) ? bucket_size[tid] : 0;
  tmp[tid] = v;
  __syncthreads();
  for (int off = 1; off < 1024; off <<= 1) {
    int t = (tid >= off) ? tmp[tid - off] : 0;
    __syncthreads();
    tmp[tid] += t;
    __syncthreads();
  }
  if (tid <= NB) bucket_offs[tid] = tmp[tid] - v;  // exclusive; offs[NB]=E
}

// ------------- Pass 3: place edges into bucket-partitioned array -------------
// Packed entry: x = src | (dst_local << 20), y = weight bits.
__global__ __launch_bounds__(256) void bucket_place_kernel(
    const int* __restrict__ src, const int* __restrict__ dst,
    const float* __restrict__ w, const int* __restrict__ bucket_offs,
    const int* __restrict__ blockRel, int2* __restrict__ bpart, int NB, int E) {
  __shared__ int cur[NBMAX];
  for (int i = threadIdx.x; i < NB; i += 256)
    cur[i] = bucket_offs[i] + blockRel[(long)blockIdx.x * NB + i];
  __syncthreads();
  int base = blockIdx.x * CH;
  int end = min(base + CH, E);
  for (int k = base + threadIdx.x; k < end; k += 256) {
    int d = dst[k];
    int b = d >> SHIFT;
    int pos = atomicAdd(&cur[b], 1);
    bpart[pos] = make_int2((src[k] & SRCMASK) | ((d & (BNODES - 1)) << 20),
                           __float_as_int(w[k]));
  }
}

// ------------- Pass 4: per-bucket CSR finalize (LDS-staged) -------------
__global__ __launch_bounds__(256) void csr_place_kernel(
    const int2* __restrict__ bpart, const int* __restrict__ bucket_offs,
    int2* __restrict__ csr, int* __restrict__ noffs, int N, int NB, int E) {
  __shared__ int cnt[BNODES];
  __shared__ int cur[BNODES];
  __shared__ int wtot[4];
  __shared__ int2 ebuf[LDSCAP];
  const int t = threadIdx.x;
  const int b = blockIdx.x;
  const int beg = bucket_offs[b], end = bucket_offs[b + 1];
  const int len = end - beg;
  const bool useLds = (len <= LDSCAP);

  cnt[t] = 0;
  __syncthreads();

  if (useLds) {
    for (int k = t; k < len; k += 256) {
      int2 e = bpart[beg + k];
      ebuf[k] = e;
      atomicAdd(&cnt[e.x >> 20], 1);
    }
  } else {
    for (int k = beg + t; k < end; k += 256)
      atomicAdd(&cnt[bpart[k].x >> 20], 1);
  }
  __syncthreads();

  // exclusive scan of cnt[0..255]: per-wave shfl scan + wave-total combine
  int v = cnt[t], s = v;
#pragma unroll
  for (int d = 1; d < 64; d <<= 1) {
    int u = __shfl_up(s, d, 64);
    if ((t & 63) >= d) s += u;
  }
  if ((t & 63) == 63) wtot[t >> 6] = s;
  __syncthreads();
  int base = 0;
  const int wv_ = t >> 6;
  if (wv_ > 0) base += wtot[0];
  if (wv_ > 1) base += wtot[1];
  if (wv_ > 2) base += wtot[2];
  const int g = beg + base + s - v;  // global exclusive offset for node t
  cur[t] = g;
  const int node = (b << SHIFT) + t;
  if (node < N) noffs[node] = g;
  if (b == NB - 1 && t == 0) noffs[N] = E;
  __syncthreads();

  if (useLds) {
    for (int k = t; k < len; k += 256) {
      int2 e = ebuf[k];
      int pos = atomicAdd(&cur[e.x >> 20], 1);
      csr[pos] = make_int2(e.x & SRCMASK, e.y);
    }
  } else {
    for (int k = beg + t; k < end; k += 256) {
      int2 e = bpart[k];
      int pos = atomicAdd(&cur[e.x >> 20], 1);
      csr[pos] = make_int2(e.x & SRCMASK, e.y);
    }
  }
}

// ---------------- Fused: h3[n] = relu(sum_e w*h1[src_e]) . W2 + b2 ----------------
// R13 structure: one 64-lane wave per node, eight 8-lane groups; each group
// handles one edge per step with uint4 loads (8 dims / lane) -> 16 edges in
// flight per wave. Butterfly-with-halving combine, relu*W2, 6-shfl reduce.
// Deterministic, accumulation order fixed by (noffs, csr).
__global__ __launch_bounds__(256) void spmm1_fused_kernel(
    const int* __restrict__ noffs, const int2* __restrict__ csr,
    const unsigned short* __restrict__ h1, const float* __restrict__ W2,
    const float* __restrict__ b2, float* __restrict__ h3, int N) {
  int wave = (blockIdx.x * 256 + threadIdx.x) >> 6;
  int lane = threadIdx.x & 63;
  if (wave >= N) return;
  int beg = noffs[wave], end = noffs[wave + 1];
  const int e8 = lane >> 3;        // eighth 0..7 (edge subset)
  const int l8 = lane & 7;         // dim group: dims 8*l8 .. 8*l8+7

  float a0 = 0.f, a1 = 0.f, a2 = 0.f, a3 = 0.f;
  float a4 = 0.f, a5 = 0.f, a6 = 0.f, a7 = 0.f;
  int k = beg + e8;

  int2 eA, eB;
  if (k + 8 < end) { eA = csr[k]; eB = csr[k + 8]; }
  while (k + 8 < end) {
    uint4 vA = *reinterpret_cast<const uint4*>(h1 + (long)eA.x * HID + 8 * l8);
    uint4 vB = *reinterpret_cast<const uint4*>(h1 + (long)eB.x * HID + 8 * l8);
    float wA = __int_as_float(eA.y), wB = __int_as_float(eB.y);
    int kn = k + 16;
    if (kn + 8 < end) { eA = csr[kn]; eB = csr[kn + 8]; }  // prefetch next pair
    a0 += wA * bf2f_lo(vA.x); a1 += wA * bf2f_hi(vA.x);
    a2 += wA * bf2f_lo(vA.y); a3 += wA * bf2f_hi(vA.y);
    a4 += wA * bf2f_lo(vA.z); a5 += wA * bf2f_hi(vA.z);
    a6 += wA * bf2f_lo(vA.w); a7 += wA * bf2f_hi(vA.w);
    a0 += wB * bf2f_lo(vB.x); a1 += wB * bf2f_hi(vB.x);
    a2 += wB * bf2f_lo(vB.y); a3 += wB * bf2f_hi(vB.y);
    a4 += wB * bf2f_lo(vB.z); a5 += wB * bf2f_hi(vB.z);
    a6 += wB * bf2f_lo(vB.w); a7 += wB * bf2f_hi(vB.w);
    k = kn;
  }
  for (; k < end; k += 8) {
    int2 e = csr[k];
    uint4 v = *reinterpret_cast<const uint4*>(h1 + (long)e.x * HID + 8 * l8);
    float w = __int_as_float(e.y);
    a0 += w * bf2f_lo(v.x); a1 += w * bf2f_hi(v.x);
    a2 += w * bf2f_lo(v.y); a3 += w * bf2f_hi(v.y);
    a4 += w * bf2f_lo(v.z); a5 += w * bf2f_hi(v.z);
    a6 += w * bf2f_lo(v.w); a7 += w * bf2f_hi(v.w);
  }

  // Butterfly combine across eighths, halving live accs each round.
  {
    const bool hi = (e8 & 1);
    float s0 = hi ? a0 : a4;  float r0 = __shfl_xor(s0, 8, 64);
    float s1 = hi ? a1 : a5;  float r1 = __shfl_xor(s1, 8, 64);
    float s2 = hi ? a2 : a6;  float r2 = __shfl_xor(s2, 8, 64);
    float s3 = hi ? a3 : a7;  float r3 = __shfl_xor(s3, 8, 64);
    a0 = (hi ? a4 : a0) + r0;
    a1 = (hi ? a5 : a1) + r1;
    a2 = (hi ? a6 : a2) + r2;
    a3 = (hi ? a7 : a3) + r3;
  }
  {
    const bool hi = (e8 >> 1) & 1;
    float s0 = hi ? a0 : a2;  float r0 = __shfl_xor(s0, 16, 64);
    float s1 = hi ? a1 : a3;  float r1 = __shfl_xor(s1, 16, 64);
    a0 = (hi ? a2 : a0) + r0;
    a1 = (hi ? a3 : a1) + r1;
  }
  {
    const bool hi = (e8 >> 2) & 1;
    float s0 = hi ? a0 : a1;  float r0 = __shfl_xor(s0, 32, 64);
    a0 = (hi ? a1 : a0) + r0;
  }
  const int dim = 8 * l8 + 4 * (e8 & 1) + 2 * ((e8 >> 1) & 1) + ((e8 >> 2) & 1);
  float s = fmaxf(a0, 0.f) * W2[dim];
  s += __shfl_xor(s, 1, 64);
  s += __shfl_xor(s, 2, 64);
  s += __shfl_xor(s, 4, 64);
  s += __shfl_xor(s, 8, 64);
  s += __shfl_xor(s, 16, 64);
  s += __shfl_xor(s, 32, 64);
  if (lane == 0) h3[wave] = s + b2[0];
}

// ---------------- Gather spmm2: out[n] = sum_e w*h3[src_e] ----------------
__global__ __launch_bounds__(256) void spmm2_gather_kernel(
    const int* __restrict__ noffs, const int2* __restrict__ csr,
    const float* __restrict__ h3, float* __restrict__ out, int N) {
  int n = blockIdx.x * 256 + threadIdx.x;
  if (n >= N) return;
  int beg = noffs[n], end = noffs[n + 1];
  float acc = 0.f;
  for (int k = beg; k < end; ++k) {
    int2 e = csr[k];
    acc += __int_as_float(e.y) * h3[e.x];
  }
  out[n] = acc;
}

extern "C" void kernel_launch(void* const* d_in, const int* in_sizes, int n_in,
                              void* d_out, int out_size, void* d_ws, size_t ws_size,
                              hipStream_t stream) {
  const float* x    = (const float*)d_in[0];
  const int*   esrc = (const int*)d_in[1];
  const int*   edst = (const int*)d_in[2];
  const float* ew   = (const float*)d_in[3];
  const float* W1   = (const float*)d_in[4];
  const float* b1   = (const float*)d_in[5];
  const float* W2   = (const float*)d_in[6];
  const float* b2   = (const float*)d_in[7];
  float* out = (float*)d_out;

  const int N = in_sizes[0] / IN_DIM;
  const int E = in_sizes[1];
  const int NB = (N + BNODES - 1) >> SHIFT;         // 391 @ N=100k
  const int PBLK = (E + CH - 1) / CH;               // 391 @ E=1.6M

  char* p = (char*)d_ws;
  auto alloc = [&](size_t bytes) {
    char* r = p;
    p += (bytes + 15) & ~(size_t)15;
    return r;
  };
  unsigned short* h1 = (unsigned short*)alloc((size_t)N * HID * sizeof(unsigned short));
  unsigned short* W1b= (unsigned short*)alloc((size_t)8192 * sizeof(unsigned short));
  float* h3          = (float*)alloc((size_t)N * sizeof(float));
  int*   bucket_size = (int*)alloc((size_t)NB * sizeof(int));
  int*   bucket_offs = (int*)alloc((size_t)(NB + 1) * sizeof(int));
  int*   noffs       = (int*)alloc((size_t)(N + 1) * sizeof(int));
  int*   blockRel    = (int*)alloc((size_t)PBLK * NB * sizeof(int));
  int2*  bpart       = (int2*)alloc((size_t)E * sizeof(int2));
  int2*  csr         = (int2*)alloc((size_t)E * sizeof(int2));

  hipMemsetAsync(bucket_size, 0, (size_t)NB * sizeof(int), stream);

  w1pack_kernel<<<32, 256, 0, stream>>>(W1, W1b);
  gemm1_kernel<<<(N + 63) / 64, 256, 0, stream>>>(x, W1b, b1, h1, N);

  bucket_count_kernel<<<PBLK, 256, 0, stream>>>(edst, bucket_size, blockRel, NB, E);
  bucket_scan_kernel<<<1, 1024, 0, stream>>>(bucket_size, bucket_offs, NB);
  bucket_place_kernel<<<PBLK, 256, 0, stream>>>(esrc, edst, ew, bucket_offs,
                                                blockRel, bpart, NB, E);
  csr_place_kernel<<<NB, 256, 0, stream>>>(bpart, bucket_offs, csr, noffs, N, NB, E);

  spmm1_fused_kernel<<<(unsigned)(((long)N * 64 + 255) / 256), 256, 0, stream>>>(
      noffs, csr, h1, W2, b2, h3, N);

  spmm2_gather_kernel<<<(N + 255) / 256, 256, 0, stream>>>(noffs, csr, h3, out, N);
}

// Round 18
// 133.898 us; speedup vs baseline: 1.2648x; 1.0090x over previous
//
#include <hip/hip_runtime.h>

#define IN_DIM 128
#define HID 64
#define SHIFT 8                 // 256 nodes per bucket
#define BNODES 256
#define NBMAX 1024              // NB=391 @ N=100k
#define CH 4096                 // edges per chunk (R9: too few chunks = TLP collapse)
#define SRCMASK 0xFFFFF         // src packed in low 20 bits (N <= 1M)
#define LDSCAP 6144             // csr_place LDS edge-staging capacity (48 KB)
#define XSTR 130                // Xs row stride in shorts

using bf16x8 = __attribute__((ext_vector_type(8))) short;   // 8 bf16 (4 VGPRs)
using f32x4  = __attribute__((ext_vector_type(4))) float;

// bf16 round-to-nearest-even
__device__ inline unsigned short f2bf(float f) {
  unsigned u = __float_as_uint(f);
  u += 0x7FFF + ((u >> 16) & 1);
  return (unsigned short)(u >> 16);
}
__device__ inline float bf2f_lo(unsigned v) {   // low bf16 of a packed u32
  return __uint_as_float(v << 16);
}
__device__ inline float bf2f_hi(unsigned v) {   // high bf16 of a packed u32
  return __uint_as_float(v & 0xFFFF0000u);
}

// R18: bijective XCD-aware block->chunk remap (m204 formula). Blocks on one
// XCD (bid%8, round-robin dispatch) get CONSECUTIVE logical chunks, so the
// small per-(chunk,bucket) bpart slices written by one XCD are contiguous
// (~4 KB spans) -> 64B lines assembled within ONE L2, no cross-XCD
// partial-dirty evictions (R3's write-amp mechanism, milder form).
__device__ inline int xcd_chunk(int bid, int nch) {
  int q = nch >> 3, r = nch & 7;
  int xcd = bid & 7, idx = bid >> 3;
  return (xcd < r) ? xcd * (q + 1) + idx : r * (q + 1) + (xcd - r) * q + idx;
}

// ---------------- Prep: pack W1 into MFMA B-fragment order ----------------
__global__ __launch_bounds__(256) void w1pack_kernel(
    const float* __restrict__ W1, unsigned short* __restrict__ W1b) {
  int idx = blockIdx.x * 256 + threadIdx.x;   // 8192 total
  if (idx >= 4 * 4 * 64 * 8) return;
  int i    = idx & 7;
  int lane = (idx >> 3) & 63;
  int kc   = (idx >> 9) & 3;
  int jt   = idx >> 11;
  int k = kc * 32 + ((lane >> 4) << 3) + i;
  int n = jt * 16 + (lane & 15);
  W1b[idx] = f2bf(W1[k * HID + n]);
}

// ---------------- Kernel 1: h1 = bf16(x @ W1 + b1) via MFMA ----------------
// R17 structure (proven): coalesced per-wave LDS staging of x, A-frags via
// ds_read_b128, B-frags from pre-packed W1b (L1-resident).
__global__ __launch_bounds__(256) void gemm1_kernel(
    const float* __restrict__ x, const unsigned short* __restrict__ W1b,
    const float* __restrict__ b1, unsigned short* __restrict__ h1, int N) {
  __shared__ unsigned short Xs[4][16][XSTR];   // 16.6 KB
  const int lane = threadIdx.x & 63;
  const int w    = threadIdx.x >> 6;           // wave id: rows 16w..16w+15
  const int rblk = blockIdx.x * 64;

  for (int it = 0; it < 8; ++it) {
    int flat = it * 64 + lane;                 // 0..511
    int row  = flat >> 5;                      // 32 float4 per row
    int c4   = (flat & 31) * 4;
    int gr = rblk + w * 16 + row;
    if (gr > N - 1) gr = N - 1;
    float4 v = *reinterpret_cast<const float4*>(x + (long)gr * IN_DIM + c4);
    ushort4 o;
    o.x = f2bf(v.x); o.y = f2bf(v.y); o.z = f2bf(v.z); o.w = f2bf(v.w);
    *reinterpret_cast<ushort4*>(&Xs[w][row][c4]) = o;
  }
  __syncthreads();

  bf16x8 a[4];
#pragma unroll
  for (int kc = 0; kc < 4; ++kc) {
    a[kc] = *reinterpret_cast<const bf16x8*>(
        &Xs[w][lane & 15][kc * 32 + ((lane >> 4) << 3)]);
  }

  const uint4* wb = reinterpret_cast<const uint4*>(W1b);
#pragma unroll
  for (int jt = 0; jt < 4; ++jt) {
    f32x4 acc = {0.f, 0.f, 0.f, 0.f};
#pragma unroll
    for (int kc = 0; kc < 4; ++kc) {
      union { uint4 q; bf16x8 v; } bu;
      bu.q = wb[(jt * 4 + kc) * 64 + lane];
      acc = __builtin_amdgcn_mfma_f32_16x16x32_bf16(a[kc], bu.v, acc, 0, 0, 0);
    }
    const int col = jt * 16 + (lane & 15);
    const float bb = b1[col];
#pragma unroll
    for (int r = 0; r < 4; ++r) {
      int row = (lane >> 4) * 4 + r;
      int gr = rblk + w * 16 + row;
      if (gr < N) h1[(long)gr * HID + col] = f2bf(acc[r] + bb);
    }
  }
}

// ------------- Bucket partition pass 1: per-chunk histogram + reservation -------------
__global__ __launch_bounds__(256) void bucket_count_kernel(
    const int* __restrict__ dst, int* __restrict__ bucket_size,
    int* __restrict__ blockRel, int NB, int E, int NCH) {
  __shared__ int hist[NBMAX];
  const int c = xcd_chunk(blockIdx.x, NCH);   // logical chunk (XCD-remapped)
  for (int i = threadIdx.x; i < NB; i += 256) hist[i] = 0;
  __syncthreads();
  int base = c * CH;
  int end = min(base + CH, E);
  for (int k = base + threadIdx.x; k < end; k += 256)
    atomicAdd(&hist[dst[k] >> SHIFT], 1);
  __syncthreads();
  for (int i = threadIdx.x; i < NB; i += 256) {
    int cv = hist[i];
    int r = cv ? atomicAdd(&bucket_size[i], cv) : 0;
    blockRel[(long)c * NB + i] = r;
  }
}

// ------------- Pass 2: exclusive scan of bucket sizes (single block) -------------
__global__ __launch_bounds__(1024) void bucket_scan_kernel(
    const int* __restrict__ bucket_size, int* __restrict__ bucket_offs, int NB) {
  __shared__ int tmp[1024];
  int tid = threadIdx.x;
  int v = (tid < NB) ? bucket_size[tid] : 0;
  tmp[tid] = v;
  __syncthreads();
  for (int off = 1; off < 1024; off <<= 1) {
    int t = (tid >= off) ? tmp[tid - off] : 0;
    __syncthreads();
    tmp[tid] += t;
    __syncthreads();
  }
  if (tid <= NB) bucket_offs[tid] = tmp[tid] - v;  // exclusive; offs[NB]=E
}

// ------------- Pass 3: place edges into bucket-partitioned array -------------
// Packed entry: x = src | (dst_local << 20), y = weight bits.
// R18: XCD-remapped chunk id -> reservations from one XCD are contiguous in
// bucket space -> bpart lines fully assembled in a single L2.
__global__ __launch_bounds__(256) void bucket_place_kernel(
    const int* __restrict__ src, const int* __restrict__ dst,
    const float* __restrict__ w, const int* __restrict__ bucket_offs,
    const int* __restrict__ blockRel, int2* __restrict__ bpart,
    int NB, int E, int NCH) {
  __shared__ int cur[NBMAX];
  const int c = xcd_chunk(blockIdx.x, NCH);   // same mapping as count
  for (int i = threadIdx.x; i < NB; i += 256)
    cur[i] = bucket_offs[i] + blockRel[(long)c * NB + i];
  __syncthreads();
  int base = c * CH;
  int end = min(base + CH, E);
  for (int k = base + threadIdx.x; k < end; k += 256) {
    int d = dst[k];
    int b = d >> SHIFT;
    int pos = atomicAdd(&cur[b], 1);
    bpart[pos] = make_int2((src[k] & SRCMASK) | ((d & (BNODES - 1)) << 20),
                           __float_as_int(w[k]));
  }
}

// ------------- Pass 4: per-bucket CSR finalize (LDS-staged) -------------
__global__ __launch_bounds__(256) void csr_place_kernel(
    const int2* __restrict__ bpart, const int* __restrict__ bucket_offs,
    int2* __restrict__ csr, int* __restrict__ noffs, int N, int NB, int E) {
  __shared__ int cnt[BNODES];
  __shared__ int cur[BNODES];
  __shared__ int wtot[4];
  __shared__ int2 ebuf[LDSCAP];
  const int t = threadIdx.x;
  const int b = blockIdx.x;
  const int beg = bucket_offs[b], end = bucket_offs[b + 1];
  const int len = end - beg;
  const bool useLds = (len <= LDSCAP);

  cnt[t] = 0;
  __syncthreads();

  if (useLds) {
    for (int k = t; k < len; k += 256) {
      int2 e = bpart[beg + k];
      ebuf[k] = e;
      atomicAdd(&cnt[e.x >> 20], 1);
    }
  } else {
    for (int k = beg + t; k < end; k += 256)
      atomicAdd(&cnt[bpart[k].x >> 20], 1);
  }
  __syncthreads();

  int v = cnt[t], s = v;
#pragma unroll
  for (int d = 1; d < 64; d <<= 1) {
    int u = __shfl_up(s, d, 64);
    if ((t & 63) >= d) s += u;
  }
  if ((t & 63) == 63) wtot[t >> 6] = s;
  __syncthreads();
  int base = 0;
  const int wv_ = t >> 6;
  if (wv_ > 0) base += wtot[0];
  if (wv_ > 1) base += wtot[1];
  if (wv_ > 2) base += wtot[2];
  const int g = beg + base + s - v;  // global exclusive offset for node t
  cur[t] = g;
  const int node = (b << SHIFT) + t;
  if (node < N) noffs[node] = g;
  if (b == NB - 1 && t == 0) noffs[N] = E;
  __syncthreads();

  if (useLds) {
    for (int k = t; k < len; k += 256) {
      int2 e = ebuf[k];
      int pos = atomicAdd(&cur[e.x >> 20], 1);
      csr[pos] = make_int2(e.x & SRCMASK, e.y);
    }
  } else {
    for (int k = beg + t; k < end; k += 256) {
      int2 e = bpart[k];
      int pos = atomicAdd(&cur[e.x >> 20], 1);
      csr[pos] = make_int2(e.x & SRCMASK, e.y);
    }
  }
}

// ---------------- Fused: h3[n] = relu(sum_e w*h1[src_e]) . W2 + b2 ----------------
// R13 structure: one 64-lane wave per node, eight 8-lane groups, uint4 loads,
// butterfly-with-halving combine, relu*W2, 6-shfl reduce. Deterministic.
__global__ __launch_bounds__(256) void spmm1_fused_kernel(
    const int* __restrict__ noffs, const int2* __restrict__ csr,
    const unsigned short* __restrict__ h1, const float* __restrict__ W2,
    const float* __restrict__ b2, float* __restrict__ h3, int N) {
  int wave = (blockIdx.x * 256 + threadIdx.x) >> 6;
  int lane = threadIdx.x & 63;
  if (wave >= N) return;
  int beg = noffs[wave], end = noffs[wave + 1];
  const int e8 = lane >> 3;        // eighth 0..7 (edge subset)
  const int l8 = lane & 7;         // dim group: dims 8*l8 .. 8*l8+7

  float a0 = 0.f, a1 = 0.f, a2 = 0.f, a3 = 0.f;
  float a4 = 0.f, a5 = 0.f, a6 = 0.f, a7 = 0.f;
  int k = beg + e8;

  int2 eA, eB;
  if (k + 8 < end) { eA = csr[k]; eB = csr[k + 8]; }
  while (k + 8 < end) {
    uint4 vA = *reinterpret_cast<const uint4*>(h1 + (long)eA.x * HID + 8 * l8);
    uint4 vB = *reinterpret_cast<const uint4*>(h1 + (long)eB.x * HID + 8 * l8);
    float wA = __int_as_float(eA.y), wB = __int_as_float(eB.y);
    int kn = k + 16;
    if (kn + 8 < end) { eA = csr[kn]; eB = csr[kn + 8]; }  // prefetch next pair
    a0 += wA * bf2f_lo(vA.x); a1 += wA * bf2f_hi(vA.x);
    a2 += wA * bf2f_lo(vA.y); a3 += wA * bf2f_hi(vA.y);
    a4 += wA * bf2f_lo(vA.z); a5 += wA * bf2f_hi(vA.z);
    a6 += wA * bf2f_lo(vA.w); a7 += wA * bf2f_hi(vA.w);
    a0 += wB * bf2f_lo(vB.x); a1 += wB * bf2f_hi(vB.x);
    a2 += wB * bf2f_lo(vB.y); a3 += wB * bf2f_hi(vB.y);
    a4 += wB * bf2f_lo(vB.z); a5 += wB * bf2f_hi(vB.z);
    a6 += wB * bf2f_lo(vB.w); a7 += wB * bf2f_hi(vB.w);
    k = kn;
  }
  for (; k < end; k += 8) {
    int2 e = csr[k];
    uint4 v = *reinterpret_cast<const uint4*>(h1 + (long)e.x * HID + 8 * l8);
    float w = __int_as_float(e.y);
    a0 += w * bf2f_lo(v.x); a1 += w * bf2f_hi(v.x);
    a2 += w * bf2f_lo(v.y); a3 += w * bf2f_hi(v.y);
    a4 += w * bf2f_lo(v.z); a5 += w * bf2f_hi(v.z);
    a6 += w * bf2f_lo(v.w); a7 += w * bf2f_hi(v.w);
  }

  {
    const bool hi = (e8 & 1);
    float s0 = hi ? a0 : a4;  float r0 = __shfl_xor(s0, 8, 64);
    float s1 = hi ? a1 : a5;  float r1 = __shfl_xor(s1, 8, 64);
    float s2 = hi ? a2 : a6;  float r2 = __shfl_xor(s2, 8, 64);
    float s3 = hi ? a3 : a7;  float r3 = __shfl_xor(s3, 8, 64);
    a0 = (hi ? a4 : a0) + r0;
    a1 = (hi ? a5 : a1) + r1;
    a2 = (hi ? a6 : a2) + r2;
    a3 = (hi ? a7 : a3) + r3;
  }
  {
    const bool hi = (e8 >> 1) & 1;
    float s0 = hi ? a0 : a2;  float r0 = __shfl_xor(s0, 16, 64);
    float s1 = hi ? a1 : a3;  float r1 = __shfl_xor(s1, 16, 64);
    a0 = (hi ? a2 : a0) + r0;
    a1 = (hi ? a3 : a1) + r1;
  }
  {
    const bool hi = (e8 >> 2) & 1;
    float s0 = hi ? a0 : a1;  float r0 = __shfl_xor(s0, 32, 64);
    a0 = (hi ? a1 : a0) + r0;
  }
  const int dim = 8 * l8 + 4 * (e8 & 1) + 2 * ((e8 >> 1) & 1) + ((e8 >> 2) & 1);
  float s = fmaxf(a0, 0.f) * W2[dim];
  s += __shfl_xor(s, 1, 64);
  s += __shfl_xor(s, 2, 64);
  s += __shfl_xor(s, 4, 64);
  s += __shfl_xor(s, 8, 64);
  s += __shfl_xor(s, 16, 64);
  s += __shfl_xor(s, 32, 64);
  if (lane == 0) h3[wave] = s + b2[0];
}

// ---------------- Gather spmm2: out[n] = sum_e w*h3[src_e] ----------------
__global__ __launch_bounds__(256) void spmm2_gather_kernel(
    const int* __restrict__ noffs, const int2* __restrict__ csr,
    const float* __restrict__ h3, float* __restrict__ out, int N) {
  int n = blockIdx.x * 256 + threadIdx.x;
  if (n >= N) return;
  int beg = noffs[n], end = noffs[n + 1];
  float acc = 0.f;
  for (int k = beg; k < end; ++k) {
    int2 e = csr[k];
    acc += __int_as_float(e.y) * h3[e.x];
  }
  out[n] = acc;
}

extern "C" void kernel_launch(void* const* d_in, const int* in_sizes, int n_in,
                              void* d_out, int out_size, void* d_ws, size_t ws_size,
                              hipStream_t stream) {
  const float* x    = (const float*)d_in[0];
  const int*   esrc = (const int*)d_in[1];
  const int*   edst = (const int*)d_in[2];
  const float* ew   = (const float*)d_in[3];
  const float* W1   = (const float*)d_in[4];
  const float* b1   = (const float*)d_in[5];
  const float* W2   = (const float*)d_in[6];
  const float* b2   = (const float*)d_in[7];
  float* out = (float*)d_out;

  const int N = in_sizes[0] / IN_DIM;
  const int E = in_sizes[1];
  const int NB = (N + BNODES - 1) >> SHIFT;         // 391 @ N=100k
  const int NCH = (E + CH - 1) / CH;                // 391 @ E=1.6M

  char* p = (char*)d_ws;
  auto alloc = [&](size_t bytes) {
    char* r = p;
    p += (bytes + 15) & ~(size_t)15;
    return r;
  };
  unsigned short* h1 = (unsigned short*)alloc((size_t)N * HID * sizeof(unsigned short));
  unsigned short* W1b= (unsigned short*)alloc((size_t)8192 * sizeof(unsigned short));
  float* h3          = (float*)alloc((size_t)N * sizeof(float));
  int*   bucket_size = (int*)alloc((size_t)NB * sizeof(int));
  int*   bucket_offs = (int*)alloc((size_t)(NB + 1) * sizeof(int));
  int*   noffs       = (int*)alloc((size_t)(N + 1) * sizeof(int));
  int*   blockRel    = (int*)alloc((size_t)NCH * NB * sizeof(int));
  int2*  bpart       = (int2*)alloc((size_t)E * sizeof(int2));
  int2*  csr         = (int2*)alloc((size_t)E * sizeof(int2));

  hipMemsetAsync(bucket_size, 0, (size_t)NB * sizeof(int), stream);

  w1pack_kernel<<<32, 256, 0, stream>>>(W1, W1b);
  gemm1_kernel<<<(N + 63) / 64, 256, 0, stream>>>(x, W1b, b1, h1, N);

  bucket_count_kernel<<<NCH, 256, 0, stream>>>(edst, bucket_size, blockRel, NB, E, NCH);
  bucket_scan_kernel<<<1, 1024, 0, stream>>>(bucket_size, bucket_offs, NB);
  bucket_place_kernel<<<NCH, 256, 0, stream>>>(esrc, edst, ew, bucket_offs,
                                               blockRel, bpart, NB, E, NCH);
  csr_place_kernel<<<NB, 256, 0, stream>>>(bpart, bucket_offs, csr, noffs, N, NB, E);

  spmm1_fused_kernel<<<(unsigned)(((long)N * 64 + 255) / 256), 256, 0, stream>>>(
      noffs, csr, h1, W2, b2, h3, N);

  spmm2_gather_kernel<<<(N + 255) / 256, 256, 0, stream>>>(noffs, csr, h3, out, N);
}

// Round 19
// 132.719 us; speedup vs baseline: 1.2760x; 1.0089x over previous
//
#include <hip/hip_runtime.h>

#define IN_DIM 128
#define HID 64
#define SHIFT 8                 // 256 nodes per bucket
#define BNODES 256
#define NBMAX 1024              // NB=391 @ N=100k
#define CH 4096                 // edges per chunk (R9: too few chunks = TLP collapse)
#define SRCMASK 0xFFFFF         // src packed in low 20 bits (N <= 1M)
#define LDSCAP 6144             // csr_place LDS edge-staging capacity (48 KB)
#define XSTR 130                // Xs row stride in shorts

using bf16x8 = __attribute__((ext_vector_type(8))) short;   // 8 bf16 (4 VGPRs)
using f32x4  = __attribute__((ext_vector_type(4))) float;

// bf16 round-to-nearest-even
__device__ inline unsigned short f2bf(float f) {
  unsigned u = __float_as_uint(f);
  u += 0x7FFF + ((u >> 16) & 1);
  return (unsigned short)(u >> 16);
}
__device__ inline float bf2f_lo(unsigned v) {   // low bf16 of a packed u32
  return __uint_as_float(v << 16);
}
__device__ inline float bf2f_hi(unsigned v) {   // high bf16 of a packed u32
  return __uint_as_float(v & 0xFFFF0000u);
}

// R18: bijective XCD-aware block->chunk remap (kept; small but positive).
__device__ inline int xcd_chunk(int bid, int nch) {
  int q = nch >> 3, r = nch & 7;
  int xcd = bid & 7, idx = bid >> 3;
  return (xcd < r) ? xcd * (q + 1) + idx : r * (q + 1) + (xcd - r) * q + idx;
}

// ---------------- Prep: pack W1 into MFMA B-fragment order + zero counters ----------------
// R19: bucket_size zeroing folded in (block 0) -> drops the memset dispatch.
__global__ __launch_bounds__(256) void w1pack_kernel(
    const float* __restrict__ W1, unsigned short* __restrict__ W1b,
    int* __restrict__ bucket_size, int NB) {
  if (blockIdx.x == 0) {
    for (int i = threadIdx.x; i < NB; i += 256) bucket_size[i] = 0;
  }
  int idx = blockIdx.x * 256 + threadIdx.x;   // 8192 total
  if (idx >= 4 * 4 * 64 * 8) return;
  int i    = idx & 7;
  int lane = (idx >> 3) & 63;
  int kc   = (idx >> 9) & 3;
  int jt   = idx >> 11;
  int k = kc * 32 + ((lane >> 4) << 3) + i;
  int n = jt * 16 + (lane & 15);
  W1b[idx] = f2bf(W1[k * HID + n]);
}

// ---------------- Kernel 1: h1 = bf16(x @ W1 + b1) via MFMA ----------------
// R17 structure (proven): coalesced per-wave LDS staging of x, A-frags via
// ds_read_b128, B-frags from pre-packed W1b (L1-resident).
__global__ __launch_bounds__(256) void gemm1_kernel(
    const float* __restrict__ x, const unsigned short* __restrict__ W1b,
    const float* __restrict__ b1, unsigned short* __restrict__ h1, int N) {
  __shared__ unsigned short Xs[4][16][XSTR];   // 16.6 KB
  const int lane = threadIdx.x & 63;
  const int w    = threadIdx.x >> 6;           // wave id: rows 16w..16w+15
  const int rblk = blockIdx.x * 64;

  for (int it = 0; it < 8; ++it) {
    int flat = it * 64 + lane;                 // 0..511
    int row  = flat >> 5;                      // 32 float4 per row
    int c4   = (flat & 31) * 4;
    int gr = rblk + w * 16 + row;
    if (gr > N - 1) gr = N - 1;
    float4 v = *reinterpret_cast<const float4*>(x + (long)gr * IN_DIM + c4);
    ushort4 o;
    o.x = f2bf(v.x); o.y = f2bf(v.y); o.z = f2bf(v.z); o.w = f2bf(v.w);
    *reinterpret_cast<ushort4*>(&Xs[w][row][c4]) = o;
  }
  __syncthreads();

  bf16x8 a[4];
#pragma unroll
  for (int kc = 0; kc < 4; ++kc) {
    a[kc] = *reinterpret_cast<const bf16x8*>(
        &Xs[w][lane & 15][kc * 32 + ((lane >> 4) << 3)]);
  }

  const uint4* wb = reinterpret_cast<const uint4*>(W1b);
#pragma unroll
  for (int jt = 0; jt < 4; ++jt) {
    f32x4 acc = {0.f, 0.f, 0.f, 0.f};
#pragma unroll
    for (int kc = 0; kc < 4; ++kc) {
      union { uint4 q; bf16x8 v; } bu;
      bu.q = wb[(jt * 4 + kc) * 64 + lane];
      acc = __builtin_amdgcn_mfma_f32_16x16x32_bf16(a[kc], bu.v, acc, 0, 0, 0);
    }
    const int col = jt * 16 + (lane & 15);
    const float bb = b1[col];
#pragma unroll
    for (int r = 0; r < 4; ++r) {
      int row = (lane >> 4) * 4 + r;
      int gr = rblk + w * 16 + row;
      if (gr < N) h1[(long)gr * HID + col] = f2bf(acc[r] + bb);
    }
  }
}

// ------------- Bucket partition pass 1: per-chunk histogram + reservation -------------
__global__ __launch_bounds__(256) void bucket_count_kernel(
    const int* __restrict__ dst, int* __restrict__ bucket_size,
    int* __restrict__ blockRel, int NB, int E, int NCH) {
  __shared__ int hist[NBMAX];
  const int c = xcd_chunk(blockIdx.x, NCH);
  for (int i = threadIdx.x; i < NB; i += 256) hist[i] = 0;
  __syncthreads();
  int base = c * CH;
  int end = min(base + CH, E);
  for (int k = base + threadIdx.x; k < end; k += 256)
    atomicAdd(&hist[dst[k] >> SHIFT], 1);
  __syncthreads();
  for (int i = threadIdx.x; i < NB; i += 256) {
    int cv = hist[i];
    int r = cv ? atomicAdd(&bucket_size[i], cv) : 0;
    blockRel[(long)c * NB + i] = r;
  }
}

// ------------- Pass 2: exclusive scan of bucket sizes (single block) -------------
__global__ __launch_bounds__(1024) void bucket_scan_kernel(
    const int* __restrict__ bucket_size, int* __restrict__ bucket_offs, int NB) {
  __shared__ int tmp[1024];
  int tid = threadIdx.x;
  int v = (tid < NB) ? bucket_size[tid] : 0;
  tmp[tid] = v;
  __syncthreads();
  for (int off = 1; off < 1024; off <<= 1) {
    int t = (tid >= off) ? tmp[tid - off] : 0;
    __syncthreads();
    tmp[tid] += t;
    __syncthreads();
  }
  if (tid <= NB) bucket_offs[tid] = tmp[tid] - v;  // exclusive; offs[NB]=E
}

// ------------- Pass 3: place edges into bucket-partitioned array -------------
__global__ __launch_bounds__(256) void bucket_place_kernel(
    const int* __restrict__ src, const int* __restrict__ dst,
    const float* __restrict__ w, const int* __restrict__ bucket_offs,
    const int* __restrict__ blockRel, int2* __restrict__ bpart,
    int NB, int E, int NCH) {
  __shared__ int cur[NBMAX];
  const int c = xcd_chunk(blockIdx.x, NCH);
  for (int i = threadIdx.x; i < NB; i += 256)
    cur[i] = bucket_offs[i] + blockRel[(long)c * NB + i];
  __syncthreads();
  int base = c * CH;
  int end = min(base + CH, E);
  for (int k = base + threadIdx.x; k < end; k += 256) {
    int d = dst[k];
    int b = d >> SHIFT;
    int pos = atomicAdd(&cur[b], 1);
    bpart[pos] = make_int2((src[k] & SRCMASK) | ((d & (BNODES - 1)) << 20),
                           __float_as_int(w[k]));
  }
}

// ------------- Pass 4: per-bucket CSR finalize (LDS-staged) -------------
__global__ __launch_bounds__(256) void csr_place_kernel(
    const int2* __restrict__ bpart, const int* __restrict__ bucket_offs,
    int2* __restrict__ csr, int* __restrict__ noffs, int N, int NB, int E) {
  __shared__ int cnt[BNODES];
  __shared__ int cur[BNODES];
  __shared__ int wtot[4];
  __shared__ int2 ebuf[LDSCAP];
  const int t = threadIdx.x;
  const int b = blockIdx.x;
  const int beg = bucket_offs[b], end = bucket_offs[b + 1];
  const int len = end - beg;
  const bool useLds = (len <= LDSCAP);

  cnt[t] = 0;
  __syncthreads();

  if (useLds) {
    for (int k = t; k < len; k += 256) {
      int2 e = bpart[beg + k];
      ebuf[k] = e;
      atomicAdd(&cnt[e.x >> 20], 1);
    }
  } else {
    for (int k = beg + t; k < end; k += 256)
      atomicAdd(&cnt[bpart[k].x >> 20], 1);
  }
  __syncthreads();

  int v = cnt[t], s = v;
#pragma unroll
  for (int d = 1; d < 64; d <<= 1) {
    int u = __shfl_up(s, d, 64);
    if ((t & 63) >= d) s += u;
  }
  if ((t & 63) == 63) wtot[t >> 6] = s;
  __syncthreads();
  int base = 0;
  const int wv_ = t >> 6;
  if (wv_ > 0) base += wtot[0];
  if (wv_ > 1) base += wtot[1];
  if (wv_ > 2) base += wtot[2];
  const int g = beg + base + s - v;  // global exclusive offset for node t
  cur[t] = g;
  const int node = (b << SHIFT) + t;
  if (node < N) noffs[node] = g;
  if (b == NB - 1 && t == 0) noffs[N] = E;
  __syncthreads();

  if (useLds) {
    for (int k = t; k < len; k += 256) {
      int2 e = ebuf[k];
      int pos = atomicAdd(&cur[e.x >> 20], 1);
      csr[pos] = make_int2(e.x & SRCMASK, e.y);
    }
  } else {
    for (int k = beg + t; k < end; k += 256) {
      int2 e = bpart[k];
      int pos = atomicAdd(&cur[e.x >> 20], 1);
      csr[pos] = make_int2(e.x & SRCMASK, e.y);
    }
  }
}

// ---------------- Fused: h3[n] = relu(sum_e w*h1[src_e]) . W2 + b2 ----------------
// R19: TWO nodes per wave, latency chains interleaved. R18 diagnosis: with
// deg~16 and 16-edge-wide processing the main loop runs ~1 iteration; each
// wave's time = one serial csr->gather->tail round-trip (~1060 cy budget vs
// ~300 cy of issue). Interleaving two nodes overlaps two chains per wave.
// Per-node accumulation order is BITWISE IDENTICAL to R13 (same k-sequence,
// same butterfly), so the output is unchanged. Deterministic.
__global__ __launch_bounds__(256) void spmm1_fused_kernel(
    const int* __restrict__ noffs, const int2* __restrict__ csr,
    const unsigned short* __restrict__ h1, const float* __restrict__ W2,
    const float* __restrict__ b2, float* __restrict__ h3, int N) {
  int wid = (blockIdx.x * 256 + threadIdx.x) >> 6;
  int lane = threadIdx.x & 63;
  const int nA = 2 * wid, nB = 2 * wid + 1;
  if (nA >= N) return;
  const bool hasB = (nB < N);
  const int e8 = lane >> 3;        // eighth 0..7 (edge subset)
  const int l8 = lane & 7;         // dim group: dims 8*l8 .. 8*l8+7

  int begA = noffs[nA], endA = noffs[nA + 1];
  int begB = hasB ? noffs[nB] : 0;
  int endB = hasB ? noffs[nB + 1] : 0;

  float aA0 = 0.f, aA1 = 0.f, aA2 = 0.f, aA3 = 0.f;
  float aA4 = 0.f, aA5 = 0.f, aA6 = 0.f, aA7 = 0.f;
  float aB0 = 0.f, aB1 = 0.f, aB2 = 0.f, aB3 = 0.f;
  float aB4 = 0.f, aB5 = 0.f, aB6 = 0.f, aB7 = 0.f;

  int kA = begA + e8, kB = begB + e8;
  int2 eA0, eA1, eB0, eB1;
  bool mA = (kA + 8 < endA);
  bool mB = hasB && (kB + 8 < endB);
  if (mA) { eA0 = csr[kA]; eA1 = csr[kA + 8]; }
  if (mB) { eB0 = csr[kB]; eB1 = csr[kB + 8]; }

  while (__any(mA | mB)) {
    uint4 vA0, vA1, vB0, vB1;
    float wA0 = 0.f, wA1 = 0.f, wB0 = 0.f, wB1 = 0.f;
    const bool dA = mA, dB = mB;
    // issue all gathers first (A then B), consume after -> chains overlap
    if (dA) {
      vA0 = *reinterpret_cast<const uint4*>(h1 + (long)eA0.x * HID + 8 * l8);
      vA1 = *reinterpret_cast<const uint4*>(h1 + (long)eA1.x * HID + 8 * l8);
      wA0 = __int_as_float(eA0.y); wA1 = __int_as_float(eA1.y);
      kA += 16; mA = (kA + 8 < endA);
      if (mA) { eA0 = csr[kA]; eA1 = csr[kA + 8]; }
    }
    if (dB) {
      vB0 = *reinterpret_cast<const uint4*>(h1 + (long)eB0.x * HID + 8 * l8);
      vB1 = *reinterpret_cast<const uint4*>(h1 + (long)eB1.x * HID + 8 * l8);
      wB0 = __int_as_float(eB0.y); wB1 = __int_as_float(eB1.y);
      kB += 16; mB = (kB + 8 < endB);
      if (mB) { eB0 = csr[kB]; eB1 = csr[kB + 8]; }
    }
    if (dA) {
      aA0 += wA0 * bf2f_lo(vA0.x); aA1 += wA0 * bf2f_hi(vA0.x);
      aA2 += wA0 * bf2f_lo(vA0.y); aA3 += wA0 * bf2f_hi(vA0.y);
      aA4 += wA0 * bf2f_lo(vA0.z); aA5 += wA0 * bf2f_hi(vA0.z);
      aA6 += wA0 * bf2f_lo(vA0.w); aA7 += wA0 * bf2f_hi(vA0.w);
      aA0 += wA1 * bf2f_lo(vA1.x); aA1 += wA1 * bf2f_hi(vA1.x);
      aA2 += wA1 * bf2f_lo(vA1.y); aA3 += wA1 * bf2f_hi(vA1.y);
      aA4 += wA1 * bf2f_lo(vA1.z); aA5 += wA1 * bf2f_hi(vA1.z);
      aA6 += wA1 * bf2f_lo(vA1.w); aA7 += wA1 * bf2f_hi(vA1.w);
    }
    if (dB) {
      aB0 += wB0 * bf2f_lo(vB0.x); aB1 += wB0 * bf2f_hi(vB0.x);
      aB2 += wB0 * bf2f_lo(vB0.y); aB3 += wB0 * bf2f_hi(vB0.y);
      aB4 += wB0 * bf2f_lo(vB0.z); aB5 += wB0 * bf2f_hi(vB0.z);
      aB6 += wB0 * bf2f_lo(vB0.w); aB7 += wB0 * bf2f_hi(vB0.w);
      aB0 += wB1 * bf2f_lo(vB1.x); aB1 += wB1 * bf2f_hi(vB1.x);
      aB2 += wB1 * bf2f_lo(vB1.y); aB3 += wB1 * bf2f_hi(vB1.y);
      aB4 += wB1 * bf2f_lo(vB1.z); aB5 += wB1 * bf2f_hi(vB1.z);
      aB6 += wB1 * bf2f_lo(vB1.w); aB7 += wB1 * bf2f_hi(vB1.w);
    }
  }
  // remainders (single-slot), same order as R13's tail loop
  for (; kA < endA; kA += 8) {
    int2 e = csr[kA];
    uint4 v = *reinterpret_cast<const uint4*>(h1 + (long)e.x * HID + 8 * l8);
    float w = __int_as_float(e.y);
    aA0 += w * bf2f_lo(v.x); aA1 += w * bf2f_hi(v.x);
    aA2 += w * bf2f_lo(v.y); aA3 += w * bf2f_hi(v.y);
    aA4 += w * bf2f_lo(v.z); aA5 += w * bf2f_hi(v.z);
    aA6 += w * bf2f_lo(v.w); aA7 += w * bf2f_hi(v.w);
  }
  if (hasB) {
    for (; kB < endB; kB += 8) {
      int2 e = csr[kB];
      uint4 v = *reinterpret_cast<const uint4*>(h1 + (long)e.x * HID + 8 * l8);
      float w = __int_as_float(e.y);
      aB0 += w * bf2f_lo(v.x); aB1 += w * bf2f_hi(v.x);
      aB2 += w * bf2f_lo(v.y); aB3 += w * bf2f_hi(v.y);
      aB4 += w * bf2f_lo(v.z); aB5 += w * bf2f_hi(v.z);
      aB6 += w * bf2f_lo(v.w); aB7 += w * bf2f_hi(v.w);
    }
  }

  // Butterfly combine (identical to R13) for A and B; independent chains.
  {
    const bool hi = (e8 & 1);
    float s0 = hi ? aA0 : aA4;  float r0 = __shfl_xor(s0, 8, 64);
    float s1 = hi ? aA1 : aA5;  float r1 = __shfl_xor(s1, 8, 64);
    float s2 = hi ? aA2 : aA6;  float r2 = __shfl_xor(s2, 8, 64);
    float s3 = hi ? aA3 : aA7;  float r3 = __shfl_xor(s3, 8, 64);
    aA0 = (hi ? aA4 : aA0) + r0;
    aA1 = (hi ? aA5 : aA1) + r1;
    aA2 = (hi ? aA6 : aA2) + r2;
    aA3 = (hi ? aA7 : aA3) + r3;
    float t0 = hi ? aB0 : aB4;  float q0 = __shfl_xor(t0, 8, 64);
    float t1 = hi ? aB1 : aB5;  float q1 = __shfl_xor(t1, 8, 64);
    float t2 = hi ? aB2 : aB6;  float q2 = __shfl_xor(t2, 8, 64);
    float t3 = hi ? aB3 : aB7;  float q3 = __shfl_xor(t3, 8, 64);
    aB0 = (hi ? aB4 : aB0) + q0;
    aB1 = (hi ? aB5 : aB1) + q1;
    aB2 = (hi ? aB6 : aB2) + q2;
    aB3 = (hi ? aB7 : aB3) + q3;
  }
  {
    const bool hi = (e8 >> 1) & 1;
    float s0 = hi ? aA0 : aA2;  float r0 = __shfl_xor(s0, 16, 64);
    float s1 = hi ? aA1 : aA3;  float r1 = __shfl_xor(s1, 16, 64);
    aA0 = (hi ? aA2 : aA0) + r0;
    aA1 = (hi ? aA3 : aA1) + r1;
    float t0 = hi ? aB0 : aB2;  float q0 = __shfl_xor(t0, 16, 64);
    float t1 = hi ? aB1 : aB3;  float q1 = __shfl_xor(t1, 16, 64);
    aB0 = (hi ? aB2 : aB0) + q0;
    aB1 = (hi ? aB3 : aB1) + q1;
  }
  {
    const bool hi = (e8 >> 2) & 1;
    float s0 = hi ? aA0 : aA1;  float r0 = __shfl_xor(s0, 32, 64);
    aA0 = (hi ? aA1 : aA0) + r0;
    float t0 = hi ? aB0 : aB1;  float q0 = __shfl_xor(t0, 32, 64);
    aB0 = (hi ? aB1 : aB0) + q0;
  }
  const int dim = 8 * l8 + 4 * (e8 & 1) + 2 * ((e8 >> 1) & 1) + ((e8 >> 2) & 1);
  const float w2 = W2[dim];
  float sA = fmaxf(aA0, 0.f) * w2;
  float sB = fmaxf(aB0, 0.f) * w2;
  sA += __shfl_xor(sA, 1, 64);   sB += __shfl_xor(sB, 1, 64);
  sA += __shfl_xor(sA, 2, 64);   sB += __shfl_xor(sB, 2, 64);
  sA += __shfl_xor(sA, 4, 64);   sB += __shfl_xor(sB, 4, 64);
  sA += __shfl_xor(sA, 8, 64);   sB += __shfl_xor(sB, 8, 64);
  sA += __shfl_xor(sA, 16, 64);  sB += __shfl_xor(sB, 16, 64);
  sA += __shfl_xor(sA, 32, 64);  sB += __shfl_xor(sB, 32, 64);
  if (lane == 0) {
    h3[nA] = sA + b2[0];
    if (hasB) h3[nB] = sB + b2[0];
  }
}

// ---------------- Gather spmm2: out[n] = sum_e w*h3[src_e] ----------------
__global__ __launch_bounds__(256) void spmm2_gather_kernel(
    const int* __restrict__ noffs, const int2* __restrict__ csr,
    const float* __restrict__ h3, float* __restrict__ out, int N) {
  int n = blockIdx.x * 256 + threadIdx.x;
  if (n >= N) return;
  int beg = noffs[n], end = noffs[n + 1];
  float acc = 0.f;
  for (int k = beg; k < end; ++k) {
    int2 e = csr[k];
    acc += __int_as_float(e.y) * h3[e.x];
  }
  out[n] = acc;
}

extern "C" void kernel_launch(void* const* d_in, const int* in_sizes, int n_in,
                              void* d_out, int out_size, void* d_ws, size_t ws_size,
                              hipStream_t stream) {
  const float* x    = (const float*)d_in[0];
  const int*   esrc = (const int*)d_in[1];
  const int*   edst = (const int*)d_in[2];
  const float* ew   = (const float*)d_in[3];
  const float* W1   = (const float*)d_in[4];
  const float* b1   = (const float*)d_in[5];
  const float* W2   = (const float*)d_in[6];
  const float* b2   = (const float*)d_in[7];
  float* out = (float*)d_out;

  const int N = in_sizes[0] / IN_DIM;
  const int E = in_sizes[1];
  const int NB = (N + BNODES - 1) >> SHIFT;         // 391 @ N=100k
  const int NCH = (E + CH - 1) / CH;                // 391 @ E=1.6M

  char* p = (char*)d_ws;
  auto alloc = [&](size_t bytes) {
    char* r = p;
    p += (bytes + 15) & ~(size_t)15;
    return r;
  };
  unsigned short* h1 = (unsigned short*)alloc((size_t)N * HID * sizeof(unsigned short));
  unsigned short* W1b= (unsigned short*)alloc((size_t)8192 * sizeof(unsigned short));
  float* h3          = (float*)alloc((size_t)N * sizeof(float));
  int*   bucket_size = (int*)alloc((size_t)NB * sizeof(int));
  int*   bucket_offs = (int*)alloc((size_t)(NB + 1) * sizeof(int));
  int*   noffs       = (int*)alloc((size_t)(N + 1) * sizeof(int));
  int*   blockRel    = (int*)alloc((size_t)NCH * NB * sizeof(int));
  int2*  bpart       = (int2*)alloc((size_t)E * sizeof(int2));
  int2*  csr         = (int2*)alloc((size_t)E * sizeof(int2));

  w1pack_kernel<<<32, 256, 0, stream>>>(W1, W1b, bucket_size, NB);
  gemm1_kernel<<<(N + 63) / 64, 256, 0, stream>>>(x, W1b, b1, h1, N);

  bucket_count_kernel<<<NCH, 256, 0, stream>>>(edst, bucket_size, blockRel, NB, E, NCH);
  bucket_scan_kernel<<<1, 1024, 0, stream>>>(bucket_size, bucket_offs, NB);
  bucket_place_kernel<<<NCH, 256, 0, stream>>>(esrc, edst, ew, bucket_offs,
                                               blockRel, bpart, NB, E, NCH);
  csr_place_kernel<<<NB, 256, 0, stream>>>(bpart, bucket_offs, csr, noffs, N, NB, E);

  {
    long waves = (N + 1) / 2;                       // 2 nodes per wave
    long blocks = (waves * 64 + 255) / 256;
    spmm1_fused_kernel<<<(unsigned)blocks, 256, 0, stream>>>(
        noffs, csr, h1, W2, b2, h3, N);
  }

  spmm2_gather_kernel<<<(N + 255) / 256, 256, 0, stream>>>(noffs, csr, h3, out, N);
}

// Round 20
// 126.428 us; speedup vs baseline: 1.3395x; 1.0498x over previous
//
#include <hip/hip_runtime.h>

#define IN_DIM 128
#define HID 64
#define SHIFT 8                 // 256 nodes per bucket
#define BNODES 256
#define NBMAX 1024              // NB=391 @ N=100k
#define CH 4096                 // edges per chunk (R9: too few chunks = TLP collapse)
#define SRCMASK 0xFFFFF         // src packed in low 20 bits (N <= 1M)
#define LDSCAP 6144             // csr_place LDS edge-staging capacity (48 KB)
#define XSTR 130                // Xs row stride in shorts

using bf16x8 = __attribute__((ext_vector_type(8))) short;   // 8 bf16 (4 VGPRs)
using f32x4  = __attribute__((ext_vector_type(4))) float;

// bf16 round-to-nearest-even
__device__ inline unsigned short f2bf(float f) {
  unsigned u = __float_as_uint(f);
  u += 0x7FFF + ((u >> 16) & 1);
  return (unsigned short)(u >> 16);
}
__device__ inline float bf2f_lo(unsigned v) {   // low bf16 of a packed u32
  return __uint_as_float(v << 16);
}
__device__ inline float bf2f_hi(unsigned v) {   // high bf16 of a packed u32
  return __uint_as_float(v & 0xFFFF0000u);
}

// R18: bijective XCD-aware block->chunk remap (kept).
__device__ inline int xcd_chunk(int bid, int nch) {
  int q = nch >> 3, r = nch & 7;
  int xcd = bid & 7, idx = bid >> 3;
  return (xcd < r) ? xcd * (q + 1) + idx : r * (q + 1) + (xcd - r) * q + idx;
}

// ---------------- Prep: pack W1 into MFMA B-fragment order + zero counters ----------------
__global__ __launch_bounds__(256) void w1pack_kernel(
    const float* __restrict__ W1, unsigned short* __restrict__ W1b,
    int* __restrict__ bucket_size, int NB) {
  if (blockIdx.x == 0) {
    for (int i = threadIdx.x; i < NB; i += 256) bucket_size[i] = 0;
  }
  int idx = blockIdx.x * 256 + threadIdx.x;   // 8192 total
  if (idx >= 4 * 4 * 64 * 8) return;
  int i    = idx & 7;
  int lane = (idx >> 3) & 63;
  int kc   = (idx >> 9) & 3;
  int jt   = idx >> 11;
  int k = kc * 32 + ((lane >> 4) << 3) + i;
  int n = jt * 16 + (lane & 15);
  W1b[idx] = f2bf(W1[k * HID + n]);
}

// ---------------- Kernel 1: h1 = bf16(x @ W1 + b1) via MFMA ----------------
// R17 structure (proven): coalesced per-wave LDS staging of x, A-frags via
// ds_read_b128, B-frags from pre-packed W1b (L1-resident).
__global__ __launch_bounds__(256) void gemm1_kernel(
    const float* __restrict__ x, const unsigned short* __restrict__ W1b,
    const float* __restrict__ b1, unsigned short* __restrict__ h1, int N) {
  __shared__ unsigned short Xs[4][16][XSTR];   // 16.6 KB
  const int lane = threadIdx.x & 63;
  const int w    = threadIdx.x >> 6;           // wave id: rows 16w..16w+15
  const int rblk = blockIdx.x * 64;

  for (int it = 0; it < 8; ++it) {
    int flat = it * 64 + lane;                 // 0..511
    int row  = flat >> 5;                      // 32 float4 per row
    int c4   = (flat & 31) * 4;
    int gr = rblk + w * 16 + row;
    if (gr > N - 1) gr = N - 1;
    float4 v = *reinterpret_cast<const float4*>(x + (long)gr * IN_DIM + c4);
    ushort4 o;
    o.x = f2bf(v.x); o.y = f2bf(v.y); o.z = f2bf(v.z); o.w = f2bf(v.w);
    *reinterpret_cast<ushort4*>(&Xs[w][row][c4]) = o;
  }
  __syncthreads();

  bf16x8 a[4];
#pragma unroll
  for (int kc = 0; kc < 4; ++kc) {
    a[kc] = *reinterpret_cast<const bf16x8*>(
        &Xs[w][lane & 15][kc * 32 + ((lane >> 4) << 3)]);
  }

  const uint4* wb = reinterpret_cast<const uint4*>(W1b);
#pragma unroll
  for (int jt = 0; jt < 4; ++jt) {
    f32x4 acc = {0.f, 0.f, 0.f, 0.f};
#pragma unroll
    for (int kc = 0; kc < 4; ++kc) {
      union { uint4 q; bf16x8 v; } bu;
      bu.q = wb[(jt * 4 + kc) * 64 + lane];
      acc = __builtin_amdgcn_mfma_f32_16x16x32_bf16(a[kc], bu.v, acc, 0, 0, 0);
    }
    const int col = jt * 16 + (lane & 15);
    const float bb = b1[col];
#pragma unroll
    for (int r = 0; r < 4; ++r) {
      int row = (lane >> 4) * 4 + r;
      int gr = rblk + w * 16 + row;
      if (gr < N) h1[(long)gr * HID + col] = f2bf(acc[r] + bb);
    }
  }
}

// ------------- Bucket partition pass 1: per-chunk histogram + reservation -------------
__global__ __launch_bounds__(256) void bucket_count_kernel(
    const int* __restrict__ dst, int* __restrict__ bucket_size,
    int* __restrict__ blockRel, int NB, int E, int NCH) {
  __shared__ int hist[NBMAX];
  const int c = xcd_chunk(blockIdx.x, NCH);
  for (int i = threadIdx.x; i < NB; i += 256) hist[i] = 0;
  __syncthreads();
  int base = c * CH;
  int end = min(base + CH, E);
  for (int k = base + threadIdx.x; k < end; k += 256)
    atomicAdd(&hist[dst[k] >> SHIFT], 1);
  __syncthreads();
  for (int i = threadIdx.x; i < NB; i += 256) {
    int cv = hist[i];
    int r = cv ? atomicAdd(&bucket_size[i], cv) : 0;
    blockRel[(long)c * NB + i] = r;
  }
}

// ------------- Pass 2: exclusive scan of bucket sizes (single block) -------------
__global__ __launch_bounds__(1024) void bucket_scan_kernel(
    const int* __restrict__ bucket_size, int* __restrict__ bucket_offs, int NB) {
  __shared__ int tmp[1024];
  int tid = threadIdx.x;
  int v = (tid < NB) ? bucket_size[tid] : 0;
  tmp[tid] = v;
  __syncthreads();
  for (int off = 1; off < 1024; off <<= 1) {
    int t = (tid >= off) ? tmp[tid - off] : 0;
    __syncthreads();
    tmp[tid] += t;
    __syncthreads();
  }
  if (tid <= NB) bucket_offs[tid] = tmp[tid] - v;  // exclusive; offs[NB]=E
}

// ------------- Pass 3: place edges into bucket-partitioned array -------------
__global__ __launch_bounds__(256) void bucket_place_kernel(
    const int* __restrict__ src, const int* __restrict__ dst,
    const float* __restrict__ w, const int* __restrict__ bucket_offs,
    const int* __restrict__ blockRel, int2* __restrict__ bpart,
    int NB, int E, int NCH) {
  __shared__ int cur[NBMAX];
  const int c = xcd_chunk(blockIdx.x, NCH);
  for (int i = threadIdx.x; i < NB; i += 256)
    cur[i] = bucket_offs[i] + blockRel[(long)c * NB + i];
  __syncthreads();
  int base = c * CH;
  int end = min(base + CH, E);
  for (int k = base + threadIdx.x; k < end; k += 256) {
    int d = dst[k];
    int b = d >> SHIFT;
    int pos = atomicAdd(&cur[b], 1);
    bpart[pos] = make_int2((src[k] & SRCMASK) | ((d & (BNODES - 1)) << 20),
                           __float_as_int(w[k]));
  }
}

// ------------- Pass 4: per-bucket CSR finalize (LDS-staged) -------------
__global__ __launch_bounds__(256) void csr_place_kernel(
    const int2* __restrict__ bpart, const int* __restrict__ bucket_offs,
    int2* __restrict__ csr, int* __restrict__ noffs, int N, int NB, int E) {
  __shared__ int cnt[BNODES];
  __shared__ int cur[BNODES];
  __shared__ int wtot[4];
  __shared__ int2 ebuf[LDSCAP];
  const int t = threadIdx.x;
  const int b = blockIdx.x;
  const int beg = bucket_offs[b], end = bucket_offs[b + 1];
  const int len = end - beg;
  const bool useLds = (len <= LDSCAP);

  cnt[t] = 0;
  __syncthreads();

  if (useLds) {
    for (int k = t; k < len; k += 256) {
      int2 e = bpart[beg + k];
      ebuf[k] = e;
      atomicAdd(&cnt[e.x >> 20], 1);
    }
  } else {
    for (int k = beg + t; k < end; k += 256)
      atomicAdd(&cnt[bpart[k].x >> 20], 1);
  }
  __syncthreads();

  int v = cnt[t], s = v;
#pragma unroll
  for (int d = 1; d < 64; d <<= 1) {
    int u = __shfl_up(s, d, 64);
    if ((t & 63) >= d) s += u;
  }
  if ((t & 63) == 63) wtot[t >> 6] = s;
  __syncthreads();
  int base = 0;
  const int wv_ = t >> 6;
  if (wv_ > 0) base += wtot[0];
  if (wv_ > 1) base += wtot[1];
  if (wv_ > 2) base += wtot[2];
  const int g = beg + base + s - v;  // global exclusive offset for node t
  cur[t] = g;
  const int node = (b << SHIFT) + t;
  if (node < N) noffs[node] = g;
  if (b == NB - 1 && t == 0) noffs[N] = E;
  __syncthreads();

  if (useLds) {
    for (int k = t; k < len; k += 256) {
      int2 e = ebuf[k];
      int pos = atomicAdd(&cur[e.x >> 20], 1);
      csr[pos] = make_int2(e.x & SRCMASK, e.y);
    }
  } else {
    for (int k = beg + t; k < end; k += 256) {
      int2 e = bpart[k];
      int pos = atomicAdd(&cur[e.x >> 20], 1);
      csr[pos] = make_int2(e.x & SRCMASK, e.y);
    }
  }
}

// ---------------- Fused: h3[n] = relu(sum_e w*h1[src_e]) . W2 + b2 ----------------
// EXACT R13 kernel (proven 43.2 us, 20 VGPR, 67% occupancy). R19 lesson:
// interleaving two nodes per wave made the main loop DIVERGENT (bounds are
// per-lane via e8) -> partial-exec serialization + VGPR 40 -> net slower.
__global__ __launch_bounds__(256) void spmm1_fused_kernel(
    const int* __restrict__ noffs, const int2* __restrict__ csr,
    const unsigned short* __restrict__ h1, const float* __restrict__ W2,
    const float* __restrict__ b2, float* __restrict__ h3, int N) {
  int wave = (blockIdx.x * 256 + threadIdx.x) >> 6;
  int lane = threadIdx.x & 63;
  if (wave >= N) return;
  int beg = noffs[wave], end = noffs[wave + 1];
  const int e8 = lane >> 3;        // eighth 0..7 (edge subset)
  const int l8 = lane & 7;         // dim group: dims 8*l8 .. 8*l8+7

  float a0 = 0.f, a1 = 0.f, a2 = 0.f, a3 = 0.f;
  float a4 = 0.f, a5 = 0.f, a6 = 0.f, a7 = 0.f;
  int k = beg + e8;

  int2 eA, eB;
  if (k + 8 < end) { eA = csr[k]; eB = csr[k + 8]; }
  while (k + 8 < end) {
    uint4 vA = *reinterpret_cast<const uint4*>(h1 + (long)eA.x * HID + 8 * l8);
    uint4 vB = *reinterpret_cast<const uint4*>(h1 + (long)eB.x * HID + 8 * l8);
    float wA = __int_as_float(eA.y), wB = __int_as_float(eB.y);
    int kn = k + 16;
    if (kn + 8 < end) { eA = csr[kn]; eB = csr[kn + 8]; }  // prefetch next pair
    a0 += wA * bf2f_lo(vA.x); a1 += wA * bf2f_hi(vA.x);
    a2 += wA * bf2f_lo(vA.y); a3 += wA * bf2f_hi(vA.y);
    a4 += wA * bf2f_lo(vA.z); a5 += wA * bf2f_hi(vA.z);
    a6 += wA * bf2f_lo(vA.w); a7 += wA * bf2f_hi(vA.w);
    a0 += wB * bf2f_lo(vB.x); a1 += wB * bf2f_hi(vB.x);
    a2 += wB * bf2f_lo(vB.y); a3 += wB * bf2f_hi(vB.y);
    a4 += wB * bf2f_lo(vB.z); a5 += wB * bf2f_hi(vB.z);
    a6 += wB * bf2f_lo(vB.w); a7 += wB * bf2f_hi(vB.w);
    k = kn;
  }
  for (; k < end; k += 8) {
    int2 e = csr[k];
    uint4 v = *reinterpret_cast<const uint4*>(h1 + (long)e.x * HID + 8 * l8);
    float w = __int_as_float(e.y);
    a0 += w * bf2f_lo(v.x); a1 += w * bf2f_hi(v.x);
    a2 += w * bf2f_lo(v.y); a3 += w * bf2f_hi(v.y);
    a4 += w * bf2f_lo(v.z); a5 += w * bf2f_hi(v.z);
    a6 += w * bf2f_lo(v.w); a7 += w * bf2f_hi(v.w);
  }

  {
    const bool hi = (e8 & 1);
    float s0 = hi ? a0 : a4;  float r0 = __shfl_xor(s0, 8, 64);
    float s1 = hi ? a1 : a5;  float r1 = __shfl_xor(s1, 8, 64);
    float s2 = hi ? a2 : a6;  float r2 = __shfl_xor(s2, 8, 64);
    float s3 = hi ? a3 : a7;  float r3 = __shfl_xor(s3, 8, 64);
    a0 = (hi ? a4 : a0) + r0;
    a1 = (hi ? a5 : a1) + r1;
    a2 = (hi ? a6 : a2) + r2;
    a3 = (hi ? a7 : a3) + r3;
  }
  {
    const bool hi = (e8 >> 1) & 1;
    float s0 = hi ? a0 : a2;  float r0 = __shfl_xor(s0, 16, 64);
    float s1 = hi ? a1 : a3;  float r1 = __shfl_xor(s1, 16, 64);
    a0 = (hi ? a2 : a0) + r0;
    a1 = (hi ? a3 : a1) + r1;
  }
  {
    const bool hi = (e8 >> 2) & 1;
    float s0 = hi ? a0 : a1;  float r0 = __shfl_xor(s0, 32, 64);
    a0 = (hi ? a1 : a0) + r0;
  }
  const int dim = 8 * l8 + 4 * (e8 & 1) + 2 * ((e8 >> 1) & 1) + ((e8 >> 2) & 1);
  float s = fmaxf(a0, 0.f) * W2[dim];
  s += __shfl_xor(s, 1, 64);
  s += __shfl_xor(s, 2, 64);
  s += __shfl_xor(s, 4, 64);
  s += __shfl_xor(s, 8, 64);
  s += __shfl_xor(s, 16, 64);
  s += __shfl_xor(s, 32, 64);
  if (lane == 0) h3[wave] = s + b2[0];
}

// ---------------- Gather spmm2: out[n] = sum_e w*h3[src_e] ----------------
// R20: csr read as int4 (2 edges per load). Ascending-k order preserved ->
// bitwise-identical to the scalar loop.
__global__ __launch_bounds__(256) void spmm2_gather_kernel(
    const int* __restrict__ noffs, const int2* __restrict__ csr,
    const float* __restrict__ h3, float* __restrict__ out, int N) {
  int n = blockIdx.x * 256 + threadIdx.x;
  if (n >= N) return;
  int beg = noffs[n], end = noffs[n + 1];
  float acc = 0.f;
  int k = beg;
  if (k < end && (k & 1)) {                       // align to int4
    int2 e = csr[k];
    acc += __int_as_float(e.y) * h3[e.x];
    ++k;
  }
  for (; k + 1 < end; k += 2) {
    int4 e2 = *reinterpret_cast<const int4*>(&csr[k]);
    acc += __int_as_float(e2.y) * h3[e2.x];
    acc += __int_as_float(e2.w) * h3[e2.z];
  }
  if (k < end) {
    int2 e = csr[k];
    acc += __int_as_float(e.y) * h3[e.x];
  }
  out[n] = acc;
}

extern "C" void kernel_launch(void* const* d_in, const int* in_sizes, int n_in,
                              void* d_out, int out_size, void* d_ws, size_t ws_size,
                              hipStream_t stream) {
  const float* x    = (const float*)d_in[0];
  const int*   esrc = (const int*)d_in[1];
  const int*   edst = (const int*)d_in[2];
  const float* ew   = (const float*)d_in[3];
  const float* W1   = (const float*)d_in[4];
  const float* b1   = (const float*)d_in[5];
  const float* W2   = (const float*)d_in[6];
  const float* b2   = (const float*)d_in[7];
  float* out = (float*)d_out;

  const int N = in_sizes[0] / IN_DIM;
  const int E = in_sizes[1];
  const int NB = (N + BNODES - 1) >> SHIFT;         // 391 @ N=100k
  const int NCH = (E + CH - 1) / CH;                // 391 @ E=1.6M

  char* p = (char*)d_ws;
  auto alloc = [&](size_t bytes) {
    char* r = p;
    p += (bytes + 15) & ~(size_t)15;
    return r;
  };
  unsigned short* h1 = (unsigned short*)alloc((size_t)N * HID * sizeof(unsigned short));
  unsigned short* W1b= (unsigned short*)alloc((size_t)8192 * sizeof(unsigned short));
  float* h3          = (float*)alloc((size_t)N * sizeof(float));
  int*   bucket_size = (int*)alloc((size_t)NB * sizeof(int));
  int*   bucket_offs = (int*)alloc((size_t)(NB + 1) * sizeof(int));
  int*   noffs       = (int*)alloc((size_t)(N + 1) * sizeof(int));
  int*   blockRel    = (int*)alloc((size_t)NCH * NB * sizeof(int));
  int2*  bpart       = (int2*)alloc((size_t)E * sizeof(int2));
  int2*  csr         = (int2*)alloc((size_t)E * sizeof(int2));

  w1pack_kernel<<<32, 256, 0, stream>>>(W1, W1b, bucket_size, NB);
  gemm1_kernel<<<(N + 63) / 64, 256, 0, stream>>>(x, W1b, b1, h1, N);

  bucket_count_kernel<<<NCH, 256, 0, stream>>>(edst, bucket_size, blockRel, NB, E, NCH);
  bucket_scan_kernel<<<1, 1024, 0, stream>>>(bucket_size, bucket_offs, NB);
  bucket_place_kernel<<<NCH, 256, 0, stream>>>(esrc, edst, ew, bucket_offs,
                                               blockRel, bpart, NB, E, NCH);
  csr_place_kernel<<<NB, 256, 0, stream>>>(bpart, bucket_offs, csr, noffs, N, NB, E);

  spmm1_fused_kernel<<<(unsigned)(((long)N * 64 + 255) / 256), 256, 0, stream>>>(
      noffs, csr, h1, W2, b2, h3, N);

  spmm2_gather_kernel<<<(N + 255) / 256, 256, 0, stream>>>(noffs, csr, h3, out, N);
}

// Round 21
// 126.334 us; speedup vs baseline: 1.3405x; 1.0007x over previous
//
#include <hip/hip_runtime.h>

#define IN_DIM 128
#define HID 64
#define SHIFT 8                 // 256 nodes per bucket
#define BNODES 256
#define NBMAX 1024              // NB=391 @ N=100k
#define CH 4096                 // edges per chunk (R9: too few chunks = TLP collapse)
#define SRCMASK 0xFFFFF         // src packed in low 20 bits (N <= 1M)
#define LDSCAP 6144             // csr_place LDS edge-staging capacity (48 KB)
#define XSTR 130                // Xs row stride in shorts

using bf16x8 = __attribute__((ext_vector_type(8))) short;   // 8 bf16 (4 VGPRs)
using f32x4  = __attribute__((ext_vector_type(4))) float;
using f32x2  = __attribute__((ext_vector_type(2))) float;

// bf16 round-to-nearest-even
__device__ inline unsigned short f2bf(float f) {
  unsigned u = __float_as_uint(f);
  u += 0x7FFF + ((u >> 16) & 1);
  return (unsigned short)(u >> 16);
}
__device__ inline float bf2f_lo(unsigned v) {   // low bf16 of a packed u32
  return __uint_as_float(v << 16);
}
__device__ inline float bf2f_hi(unsigned v) {   // high bf16 of a packed u32
  return __uint_as_float(v & 0xFFFF0000u);
}
__device__ inline f32x2 unpk2(unsigned v) {     // {lo, hi} as f32 pair
  return (f32x2){bf2f_lo(v), bf2f_hi(v)};
}

// R18: bijective XCD-aware block->chunk remap (kept).
__device__ inline int xcd_chunk(int bid, int nch) {
  int q = nch >> 3, r = nch & 7;
  int xcd = bid & 7, idx = bid >> 3;
  return (xcd < r) ? xcd * (q + 1) + idx : r * (q + 1) + (xcd - r) * q + idx;
}

// ---------------- Kernel 1: h1 = bf16(x @ W1 + b1) via MFMA ----------------
// R21: W1 packing folded in (each block packs W1 -> LDS B-frags itself; W1 is
// a 32 KB L2-hot broadcast, ~1.5 us aggregate) -> kills the w1pack launch and
// the W1b global round-trip. bucket_size zeroing moved here (block 0).
// R17 structure otherwise: coalesced per-wave LDS staging of x, A-frags via
// ds_read_b128. R7 lesson: no cross-stage fusion beyond this (replay diverg.).
__global__ __launch_bounds__(256) void gemm1_kernel(
    const float* __restrict__ x, const float* __restrict__ W1,
    const float* __restrict__ b1, unsigned short* __restrict__ h1, int N,
    int* __restrict__ bucket_size, int NB) {
  __shared__ unsigned short Xs[4][16][XSTR];   // 16.6 KB
  __shared__ unsigned short Wb[8192];          // 16 KB B-frags
  const int lane = threadIdx.x & 63;
  const int w    = threadIdx.x >> 6;           // wave id: rows 16w..16w+15
  const int rblk = blockIdx.x * 64;

  if (blockIdx.x == 0) {
    for (int i = threadIdx.x; i < NB; i += 256) bucket_size[i] = 0;
  }

  // pack W1 -> LDS fragment order: idx = ((jt*4+kc)*64 + lane)*8 + i,
  // element = W1[(kc*32 + (lane>>4)*8 + i)*HID + jt*16 + (lane&15)]
  for (int idx = threadIdx.x; idx < 8192; idx += 256) {
    int i  = idx & 7;
    int ln = (idx >> 3) & 63;
    int kc = (idx >> 9) & 3;
    int jt = idx >> 11;
    int k = kc * 32 + ((ln >> 4) << 3) + i;
    int n = jt * 16 + (ln & 15);
    Wb[idx] = f2bf(W1[k * HID + n]);
  }

  for (int it = 0; it < 8; ++it) {
    int flat = it * 64 + lane;                 // 0..511
    int row  = flat >> 5;                      // 32 float4 per row
    int c4   = (flat & 31) * 4;
    int gr = rblk + w * 16 + row;
    if (gr > N - 1) gr = N - 1;
    float4 v = *reinterpret_cast<const float4*>(x + (long)gr * IN_DIM + c4);
    ushort4 o;
    o.x = f2bf(v.x); o.y = f2bf(v.y); o.z = f2bf(v.z); o.w = f2bf(v.w);
    *reinterpret_cast<ushort4*>(&Xs[w][row][c4]) = o;
  }
  __syncthreads();

  bf16x8 a[4];
#pragma unroll
  for (int kc = 0; kc < 4; ++kc) {
    a[kc] = *reinterpret_cast<const bf16x8*>(
        &Xs[w][lane & 15][kc * 32 + ((lane >> 4) << 3)]);
  }

  const uint4* wb = reinterpret_cast<const uint4*>(Wb);
#pragma unroll
  for (int jt = 0; jt < 4; ++jt) {
    f32x4 acc = {0.f, 0.f, 0.f, 0.f};
#pragma unroll
    for (int kc = 0; kc < 4; ++kc) {
      union { uint4 q; bf16x8 v; } bu;
      bu.q = wb[(jt * 4 + kc) * 64 + lane];
      acc = __builtin_amdgcn_mfma_f32_16x16x32_bf16(a[kc], bu.v, acc, 0, 0, 0);
    }
    const int col = jt * 16 + (lane & 15);
    const float bb = b1[col];
#pragma unroll
    for (int r = 0; r < 4; ++r) {
      int row = (lane >> 4) * 4 + r;
      int gr = rblk + w * 16 + row;
      if (gr < N) h1[(long)gr * HID + col] = f2bf(acc[r] + bb);
    }
  }
}

// ------------- Bucket partition pass 1: per-chunk histogram + reservation -------------
// R21: edst read 4 edges per int4 load (issue-bound loop).
__global__ __launch_bounds__(256) void bucket_count_kernel(
    const int* __restrict__ dst, int* __restrict__ bucket_size,
    int* __restrict__ blockRel, int NB, int E, int NCH) {
  __shared__ int hist[NBMAX];
  const int c = xcd_chunk(blockIdx.x, NCH);
  for (int i = threadIdx.x; i < NB; i += 256) hist[i] = 0;
  __syncthreads();
  int base = c * CH;
  int end = min(base + CH, E);
  for (int k = base + threadIdx.x * 4; k + 3 < end; k += 1024) {
    int4 d4 = *reinterpret_cast<const int4*>(&dst[k]);
    atomicAdd(&hist[d4.x >> SHIFT], 1);
    atomicAdd(&hist[d4.y >> SHIFT], 1);
    atomicAdd(&hist[d4.z >> SHIFT], 1);
    atomicAdd(&hist[d4.w >> SHIFT], 1);
  }
  // tail (end-base not multiple of 4 only possible in last chunk)
  int tail_start = base + ((end - base) & ~3);
  for (int k = tail_start + threadIdx.x; k < end; k += 256)
    atomicAdd(&hist[dst[k] >> SHIFT], 1);
  __syncthreads();
  for (int i = threadIdx.x; i < NB; i += 256) {
    int cv = hist[i];
    int r = cv ? atomicAdd(&bucket_size[i], cv) : 0;
    blockRel[(long)c * NB + i] = r;
  }
}

// ------------- Pass 2: exclusive scan of bucket sizes (single block) -------------
__global__ __launch_bounds__(1024) void bucket_scan_kernel(
    const int* __restrict__ bucket_size, int* __restrict__ bucket_offs, int NB) {
  __shared__ int tmp[1024];
  int tid = threadIdx.x;
  int v = (tid < NB) ? bucket_size[tid] : 0;
  tmp[tid] = v;
  __syncthreads();
  for (int off = 1; off < 1024; off <<= 1) {
    int t = (tid >= off) ? tmp[tid - off] : 0;
    __syncthreads();
    tmp[tid] += t;
    __syncthreads();
  }
  if (tid <= NB) bucket_offs[tid] = tmp[tid] - v;  // exclusive; offs[NB]=E
}

// ------------- Pass 3: place edges into bucket-partitioned array -------------
// R21: 4 edges per iteration via int4/float4 loads.
__global__ __launch_bounds__(256) void bucket_place_kernel(
    const int* __restrict__ src, const int* __restrict__ dst,
    const float* __restrict__ w, const int* __restrict__ bucket_offs,
    const int* __restrict__ blockRel, int2* __restrict__ bpart,
    int NB, int E, int NCH) {
  __shared__ int cur[NBMAX];
  const int c = xcd_chunk(blockIdx.x, NCH);
  for (int i = threadIdx.x; i < NB; i += 256)
    cur[i] = bucket_offs[i] + blockRel[(long)c * NB + i];
  __syncthreads();
  int base = c * CH;
  int end = min(base + CH, E);
  for (int k = base + threadIdx.x * 4; k + 3 < end; k += 1024) {
    int4   s4 = *reinterpret_cast<const int4*>(&src[k]);
    int4   d4 = *reinterpret_cast<const int4*>(&dst[k]);
    float4 w4 = *reinterpret_cast<const float4*>(&w[k]);
    int p0 = atomicAdd(&cur[d4.x >> SHIFT], 1);
    int p1 = atomicAdd(&cur[d4.y >> SHIFT], 1);
    int p2 = atomicAdd(&cur[d4.z >> SHIFT], 1);
    int p3 = atomicAdd(&cur[d4.w >> SHIFT], 1);
    bpart[p0] = make_int2((s4.x & SRCMASK) | ((d4.x & (BNODES - 1)) << 20),
                          __float_as_int(w4.x));
    bpart[p1] = make_int2((s4.y & SRCMASK) | ((d4.y & (BNODES - 1)) << 20),
                          __float_as_int(w4.y));
    bpart[p2] = make_int2((s4.z & SRCMASK) | ((d4.z & (BNODES - 1)) << 20),
                          __float_as_int(w4.z));
    bpart[p3] = make_int2((s4.w & SRCMASK) | ((d4.w & (BNODES - 1)) << 20),
                          __float_as_int(w4.w));
  }
  int tail_start = base + ((end - base) & ~3);
  for (int k = tail_start + threadIdx.x; k < end; k += 256) {
    int d = dst[k];
    int b = d >> SHIFT;
    int pos = atomicAdd(&cur[b], 1);
    bpart[pos] = make_int2((src[k] & SRCMASK) | ((d & (BNODES - 1)) << 20),
                           __float_as_int(w[k]));
  }
}

// ------------- Pass 4: per-bucket CSR finalize (LDS-staged) -------------
__global__ __launch_bounds__(256) void csr_place_kernel(
    const int2* __restrict__ bpart, const int* __restrict__ bucket_offs,
    int2* __restrict__ csr, int* __restrict__ noffs, int N, int NB, int E) {
  __shared__ int cnt[BNODES];
  __shared__ int cur[BNODES];
  __shared__ int wtot[4];
  __shared__ int2 ebuf[LDSCAP];
  const int t = threadIdx.x;
  const int b = blockIdx.x;
  const int beg = bucket_offs[b], end = bucket_offs[b + 1];
  const int len = end - beg;
  const bool useLds = (len <= LDSCAP);

  cnt[t] = 0;
  __syncthreads();

  if (useLds) {
    for (int k = t; k < len; k += 256) {
      int2 e = bpart[beg + k];
      ebuf[k] = e;
      atomicAdd(&cnt[e.x >> 20], 1);
    }
  } else {
    for (int k = beg + t; k < end; k += 256)
      atomicAdd(&cnt[bpart[k].x >> 20], 1);
  }
  __syncthreads();

  int v = cnt[t], s = v;
#pragma unroll
  for (int d = 1; d < 64; d <<= 1) {
    int u = __shfl_up(s, d, 64);
    if ((t & 63) >= d) s += u;
  }
  if ((t & 63) == 63) wtot[t >> 6] = s;
  __syncthreads();
  int base = 0;
  const int wv_ = t >> 6;
  if (wv_ > 0) base += wtot[0];
  if (wv_ > 1) base += wtot[1];
  if (wv_ > 2) base += wtot[2];
  const int g = beg + base + s - v;  // global exclusive offset for node t
  cur[t] = g;
  const int node = (b << SHIFT) + t;
  if (node < N) noffs[node] = g;
  if (b == NB - 1 && t == 0) noffs[N] = E;
  __syncthreads();

  if (useLds) {
    for (int k = t; k < len; k += 256) {
      int2 e = ebuf[k];
      int pos = atomicAdd(&cur[e.x >> 20], 1);
      csr[pos] = make_int2(e.x & SRCMASK, e.y);
    }
  } else {
    for (int k = beg + t; k < end; k += 256) {
      int2 e = bpart[k];
      int pos = atomicAdd(&cur[e.x >> 20], 1);
      csr[pos] = make_int2(e.x & SRCMASK, e.y);
    }
  }
}

// ---------------- Fused: h3[n] = relu(sum_e w*h1[src_e]) . W2 + b2 ----------------
// R13 structure (proven 43.2 us). R21: accumulators as f32x2 pairs -> clang
// emits v_pk_fma_f32 (2 FMA / instr), cutting inner-loop VALU ~25%
// (VALUBusy was 57%). Element-wise accumulation order unchanged.
__global__ __launch_bounds__(256) void spmm1_fused_kernel(
    const int* __restrict__ noffs, const int2* __restrict__ csr,
    const unsigned short* __restrict__ h1, const float* __restrict__ W2,
    const float* __restrict__ b2, float* __restrict__ h3, int N) {
  int wave = (blockIdx.x * 256 + threadIdx.x) >> 6;
  int lane = threadIdx.x & 63;
  if (wave >= N) return;
  int beg = noffs[wave], end = noffs[wave + 1];
  const int e8 = lane >> 3;        // eighth 0..7 (edge subset)
  const int l8 = lane & 7;         // dim group: dims 8*l8 .. 8*l8+7

  f32x2 a01 = {0.f, 0.f}, a23 = {0.f, 0.f};
  f32x2 a45 = {0.f, 0.f}, a67 = {0.f, 0.f};
  int k = beg + e8;

  int2 eA, eB;
  if (k + 8 < end) { eA = csr[k]; eB = csr[k + 8]; }
  while (k + 8 < end) {
    uint4 vA = *reinterpret_cast<const uint4*>(h1 + (long)eA.x * HID + 8 * l8);
    uint4 vB = *reinterpret_cast<const uint4*>(h1 + (long)eB.x * HID + 8 * l8);
    float wA = __int_as_float(eA.y), wB = __int_as_float(eB.y);
    int kn = k + 16;
    if (kn + 8 < end) { eA = csr[kn]; eB = csr[kn + 8]; }  // prefetch next pair
    f32x2 wA2 = {wA, wA}, wB2 = {wB, wB};
    a01 += wA2 * unpk2(vA.x);
    a23 += wA2 * unpk2(vA.y);
    a45 += wA2 * unpk2(vA.z);
    a67 += wA2 * unpk2(vA.w);
    a01 += wB2 * unpk2(vB.x);
    a23 += wB2 * unpk2(vB.y);
    a45 += wB2 * unpk2(vB.z);
    a67 += wB2 * unpk2(vB.w);
    k = kn;
  }
  for (; k < end; k += 8) {
    int2 e = csr[k];
    uint4 v = *reinterpret_cast<const uint4*>(h1 + (long)e.x * HID + 8 * l8);
    float w = __int_as_float(e.y);
    f32x2 w2v = {w, w};
    a01 += w2v * unpk2(v.x);
    a23 += w2v * unpk2(v.y);
    a45 += w2v * unpk2(v.z);
    a67 += w2v * unpk2(v.w);
  }

  float a0 = a01[0], a1 = a01[1], a2 = a23[0], a3 = a23[1];
  float a4 = a45[0], a5 = a45[1], a6 = a67[0], a7 = a67[1];

  {
    const bool hi = (e8 & 1);
    float s0 = hi ? a0 : a4;  float r0 = __shfl_xor(s0, 8, 64);
    float s1 = hi ? a1 : a5;  float r1 = __shfl_xor(s1, 8, 64);
    float s2 = hi ? a2 : a6;  float r2 = __shfl_xor(s2, 8, 64);
    float s3 = hi ? a3 : a7;  float r3 = __shfl_xor(s3, 8, 64);
    a0 = (hi ? a4 : a0) + r0;
    a1 = (hi ? a5 : a1) + r1;
    a2 = (hi ? a6 : a2) + r2;
    a3 = (hi ? a7 : a3) + r3;
  }
  {
    const bool hi = (e8 >> 1) & 1;
    float s0 = hi ? a0 : a2;  float r0 = __shfl_xor(s0, 16, 64);
    float s1 = hi ? a1 : a3;  float r1 = __shfl_xor(s1, 16, 64);
    a0 = (hi ? a2 : a0) + r0;
    a1 = (hi ? a3 : a1) + r1;
  }
  {
    const bool hi = (e8 >> 2) & 1;
    float s0 = hi ? a0 : a1;  float r0 = __shfl_xor(s0, 32, 64);
    a0 = (hi ? a1 : a0) + r0;
  }
  const int dim = 8 * l8 + 4 * (e8 & 1) + 2 * ((e8 >> 1) & 1) + ((e8 >> 2) & 1);
  float s = fmaxf(a0, 0.f) * W2[dim];
  s += __shfl_xor(s, 1, 64);
  s += __shfl_xor(s, 2, 64);
  s += __shfl_xor(s, 4, 64);
  s += __shfl_xor(s, 8, 64);
  s += __shfl_xor(s, 16, 64);
  s += __shfl_xor(s, 32, 64);
  if (lane == 0) h3[wave] = s + b2[0];
}

// ---------------- Gather spmm2: out[n] = sum_e w*h3[src_e] ----------------
__global__ __launch_bounds__(256) void spmm2_gather_kernel(
    const int* __restrict__ noffs, const int2* __restrict__ csr,
    const float* __restrict__ h3, float* __restrict__ out, int N) {
  int n = blockIdx.x * 256 + threadIdx.x;
  if (n >= N) return;
  int beg = noffs[n], end = noffs[n + 1];
  float acc = 0.f;
  int k = beg;
  if (k < end && (k & 1)) {                       // align to int4
    int2 e = csr[k];
    acc += __int_as_float(e.y) * h3[e.x];
    ++k;
  }
  for (; k + 1 < end; k += 2) {
    int4 e2 = *reinterpret_cast<const int4*>(&csr[k]);
    acc += __int_as_float(e2.y) * h3[e2.x];
    acc += __int_as_float(e2.w) * h3[e2.z];
  }
  if (k < end) {
    int2 e = csr[k];
    acc += __int_as_float(e.y) * h3[e.x];
  }
  out[n] = acc;
}

extern "C" void kernel_launch(void* const* d_in, const int* in_sizes, int n_in,
                              void* d_out, int out_size, void* d_ws, size_t ws_size,
                              hipStream_t stream) {
  const float* x    = (const float*)d_in[0];
  const int*   esrc = (const int*)d_in[1];
  const int*   edst = (const int*)d_in[2];
  const float* ew   = (const float*)d_in[3];
  const float* W1   = (const float*)d_in[4];
  const float* b1   = (const float*)d_in[5];
  const float* W2   = (const float*)d_in[6];
  const float* b2   = (const float*)d_in[7];
  float* out = (float*)d_out;

  const int N = in_sizes[0] / IN_DIM;
  const int E = in_sizes[1];
  const int NB = (N + BNODES - 1) >> SHIFT;         // 391 @ N=100k
  const int NCH = (E + CH - 1) / CH;                // 391 @ E=1.6M

  char* p = (char*)d_ws;
  auto alloc = [&](size_t bytes) {
    char* r = p;
    p += (bytes + 15) & ~(size_t)15;
    return r;
  };
  unsigned short* h1 = (unsigned short*)alloc((size_t)N * HID * sizeof(unsigned short));
  float* h3          = (float*)alloc((size_t)N * sizeof(float));
  int*   bucket_size = (int*)alloc((size_t)NB * sizeof(int));
  int*   bucket_offs = (int*)alloc((size_t)(NB + 1) * sizeof(int));
  int*   noffs       = (int*)alloc((size_t)(N + 1) * sizeof(int));
  int*   blockRel    = (int*)alloc((size_t)NCH * NB * sizeof(int));
  int2*  bpart       = (int2*)alloc((size_t)E * sizeof(int2));
  int2*  csr         = (int2*)alloc((size_t)E * sizeof(int2));

  gemm1_kernel<<<(N + 63) / 64, 256, 0, stream>>>(x, W1, b1, h1, N,
                                                  bucket_size, NB);

  bucket_count_kernel<<<NCH, 256, 0, stream>>>(edst, bucket_size, blockRel, NB, E, NCH);
  bucket_scan_kernel<<<1, 1024, 0, stream>>>(bucket_size, bucket_offs, NB);
  bucket_place_kernel<<<NCH, 256, 0, stream>>>(esrc, edst, ew, bucket_offs,
                                               blockRel, bpart, NB, E, NCH);
  csr_place_kernel<<<NB, 256, 0, stream>>>(bpart, bucket_offs, csr, noffs, N, NB, E);

  spmm1_fused_kernel<<<(unsigned)(((long)N * 64 + 255) / 256), 256, 0, stream>>>(
      noffs, csr, h1, W2, b2, h3, N);

  spmm2_gather_kernel<<<(N + 255) / 256, 256, 0, stream>>>(noffs, csr, h3, out, N);
}